// Round 6
// baseline (264.354 us; speedup 1.0000x reference)
//
#include <hip/hip_runtime.h>
#include <math.h>

#define CDIM 2048
#define HF 24
#define WF 24
#define PIX 576
#define HO 18
#define WO 18
#define NP 324
#define NHEAD 32
#define HD 64
#define NTOK 50
#define NTXT 45
#define OUTD 512
#define NKV 626
#define HJ (NHEAD * NTXT)   // 1440
#define NROWS 640           // padded B rows: 576 pixels + 50 pos + 14 zero

typedef __attribute__((ext_vector_type(8))) short short8;
typedef __attribute__((ext_vector_type(4))) float f32x4;
typedef __attribute__((address_space(1))) const void as1c_void;
typedef __attribute__((address_space(3))) void as3_void;

__device__ inline unsigned bf16rn(float x) {
    unsigned u = __float_as_uint(x);
    return (u + 0x7FFFu + ((u >> 16) & 1u)) >> 16;
}
__device__ inline float bf16tof(unsigned h) { return __uint_as_float(h << 16); }

// ---------------------------------------------------------------------------
// Split the 3 weight matrices into hi/lo bf16 (same [m][k] layout).
__global__ void split_w_k(const float* __restrict__ kw, const float* __restrict__ vw, const float* __restrict__ qw,
                          ushort* __restrict__ WhK, ushort* __restrict__ WlK,
                          ushort* __restrict__ WhV, ushort* __restrict__ WlV,
                          ushort* __restrict__ WhQ, ushort* __restrict__ WlQ) {
    int g = blockIdx.x * 256 + threadIdx.x;      // 3 * 1048576 threads, 4 elems each
    int sel = g >> 20;
    int off = (g & 1048575) * 4;
    const float* src = sel == 0 ? kw : sel == 1 ? vw : qw;
    ushort* dh = sel == 0 ? WhK : sel == 1 ? WhV : WhQ;
    ushort* dl = sel == 0 ? WlK : sel == 1 ? WlV : WlQ;
    float4 v = *(const float4*)(src + off);
    float xs[4] = {v.x, v.y, v.z, v.w};
    ushort h[4], l[4];
#pragma unroll
    for (int i = 0; i < 4; ++i) {
        unsigned hh = bf16rn(xs[i]);
        h[i] = (ushort)hh;
        l[i] = (ushort)bf16rn(xs[i] - bf16tof(hh));
    }
    *(ushort4*)(dh + off) = make_ushort4(h[0], h[1], h[2], h[3]);
    *(ushort4*)(dl + off) = make_ushort4(l[0], l[1], l[2], l[3]);
}

// ---------------------------------------------------------------------------
// Transpose+split feat1 [2048][576] f32 -> Xh/Xl [640][2048] bf16 rows 0..575.
__global__ __launch_bounds__(256) void split_xt_k(const float* __restrict__ feat1,
                                                  ushort* __restrict__ Xh, ushort* __restrict__ Xl) {
    __shared__ float tile[64][65];
    int n0 = blockIdx.x * 64, c0 = blockIdx.y * 64, tid = threadIdx.x;
#pragma unroll
    for (int i = 0; i < 16; ++i) {
        int idx = tid + i * 256;
        int cc = idx >> 6, nn = idx & 63;
        tile[cc][nn] = feat1[(size_t)(c0 + cc) * PIX + n0 + nn];
    }
    __syncthreads();
#pragma unroll
    for (int i = 0; i < 16; ++i) {
        int idx = tid + i * 256;
        int nn = idx >> 6, cc = idx & 63;
        float x = tile[cc][nn];
        unsigned hh = bf16rn(x);
        Xh[(size_t)(n0 + nn) * CDIM + c0 + cc] = (ushort)hh;
        Xl[(size_t)(n0 + nn) * CDIM + c0 + cc] = (ushort)bf16rn(x - bf16tof(hh));
    }
}

// ---------------------------------------------------------------------------
// Rows 576..639 of Xh/Xl: pos tokens (split) for r<50, zeros for pad rows.
__global__ void split_pos_k(const float* __restrict__ pos,
                            ushort* __restrict__ Xh, ushort* __restrict__ Xl) {
    int g = blockIdx.x * 256 + threadIdx.x;     // 32768 threads, 4 elems each
    int r = g >> 9;                              // 0..63
    int c = (g & 511) * 4;
    float4 v = make_float4(0.f, 0.f, 0.f, 0.f);
    if (r < 50) v = *(const float4*)(pos + (size_t)r * CDIM + c);
    float xs[4] = {v.x, v.y, v.z, v.w};
    ushort h[4], l[4];
#pragma unroll
    for (int i = 0; i < 4; ++i) {
        unsigned hh = bf16rn(xs[i]);
        h[i] = (ushort)hh;
        l[i] = (ushort)bf16rn(xs[i] - bf16tof(hh));
    }
    size_t o = (size_t)(576 + r) * CDIM + c;
    *(ushort4*)(Xh + o) = make_ushort4(h[0], h[1], h[2], h[3]);
    *(ushort4*)(Xl + o) = make_ushort4(l[0], l[1], l[2], l[3]);
}

// ---------------------------------------------------------------------------
// Split-bf16 MFMA GEMM, 3-buffer depth-2 pipeline with counted vmcnt:
//   out[n][m] = sum_k W[m][k]*X[n][k]   (X pre-transposed [n][k])
// 3 products: WhXh + WhXl + WlXh. Tile 128m x 64n, BK=32, 4 waves (2x2, wave=64x32).
// Per iter t: stage tile t+2 -> buf[(t+2)%3]; compute tile t from buf[t%3];
// s_waitcnt vmcnt(6) (tile t+1 done, t+2 in flight -- never drain to 0); s_barrier.
#define BUFB 24576
__global__ __launch_bounds__(256, 2) void gemm_bf16_k(
    const ushort* __restrict__ WhK, const ushort* __restrict__ WlK,
    const ushort* __restrict__ WhV, const ushort* __restrict__ WlV,
    const ushort* __restrict__ WhQ, const ushort* __restrict__ WlQ,
    const ushort* __restrict__ Xh, const ushort* __restrict__ Xl,
    const float* __restrict__ k_b, const float* __restrict__ v_b, const float* __restrict__ q_b,
    float* __restrict__ Kbuf, float* __restrict__ Vbuf, float* __restrict__ Qfull)
{
    __shared__ char smem[3 * BUFB];   // 72 KB: 3 rotating tile buffers
    int z = blockIdx.z;
    const ushort* Wh = z == 0 ? WhK : z == 1 ? WhV : WhQ;
    const ushort* Wl = z == 0 ? WlK : z == 1 ? WlV : WlQ;
    const float* bias = z == 0 ? k_b : z == 1 ? v_b : q_b;
    float* out = z == 0 ? Kbuf : z == 1 ? Vbuf : Qfull;
    int m0 = blockIdx.x * 128, n0 = blockIdx.y * 64;

    int tid = threadIdx.x, wid = tid >> 6, lane = tid & 63;
    int lrow = lane & 15, lk = lane >> 4;
    int wm = wid >> 1, wn = wid & 1;

    // per-wave staging assignment: 24 slot-loads/block, 6 per wave.
    const char* gsrc[6];
    int ldsoff[6];
#pragma unroll
    for (int i = 0; i < 6; ++i) {
        int g = wid * 6 + i;
        const ushort* src; int row; int off;
        if (g < 8)       { src = Wh; row = m0 + g * 16 + lrow;        off = g * 1024; }
        else if (g < 16) { src = Wl; row = m0 + (g - 8) * 16 + lrow;  off = 8192 + (g - 8) * 1024; }
        else if (g < 20) { src = Xh; row = n0 + (g - 16) * 16 + lrow; off = 16384 + (g - 16) * 1024; }
        else             { src = Xl; row = n0 + (g - 20) * 16 + lrow; off = 20480 + (g - 20) * 1024; }
        gsrc[i] = (const char*)(src + (size_t)row * CDIM + lk * 8);
        ldsoff[i] = off;
    }

    f32x4 acc[4][2];
#pragma unroll
    for (int a = 0; a < 4; ++a)
#pragma unroll
        for (int b = 0; b < 2; ++b) acc[a][b] = (f32x4)0.f;

    // prologue: stage tiles 0 and 1 into buffers 0 and 1
#pragma unroll
    for (int i = 0; i < 6; ++i)
        __builtin_amdgcn_global_load_lds((as1c_void*)(gsrc[i]),
                                         (as3_void*)(smem + ldsoff[i]), 16, 0, 0);
#pragma unroll
    for (int i = 0; i < 6; ++i)
        __builtin_amdgcn_global_load_lds((as1c_void*)(gsrc[i] + 64),
                                         (as3_void*)(smem + BUFB + ldsoff[i]), 16, 0, 0);
    asm volatile("s_waitcnt vmcnt(6)" ::: "memory");   // tile 0 complete
    __builtin_amdgcn_s_barrier();
    asm volatile("" ::: "memory");

    for (int t = 0; t < 64; ++t) {
        char* rbuf = smem + (t % 3) * BUFB;
        // stage tile t+2 into the buffer freed by tile t-1 (barrier'd)
        if (t < 62) {
            char* wbuf = smem + ((t + 2) % 3) * BUFB;
#pragma unroll
            for (int i = 0; i < 6; ++i)
                __builtin_amdgcn_global_load_lds((as1c_void*)(gsrc[i] + (size_t)(t + 2) * 64),
                                                 (as3_void*)(wbuf + ldsoff[i]), 16, 0, 0);
        }

        short8 ah[4], al[4];
#pragma unroll
        for (int fm = 0; fm < 4; ++fm) {
            int s = wm * 4 + fm;
            ah[fm] = *(const short8*)(rbuf + s * 1024 + lane * 16);
            al[fm] = *(const short8*)(rbuf + 8192 + s * 1024 + lane * 16);
        }
        short8 bh[2], bl[2];
#pragma unroll
        for (int fn = 0; fn < 2; ++fn) {
            int s = wn * 2 + fn;
            bh[fn] = *(const short8*)(rbuf + 16384 + s * 1024 + lane * 16);
            bl[fn] = *(const short8*)(rbuf + 20480 + s * 1024 + lane * 16);
        }
#pragma unroll
        for (int fn = 0; fn < 2; ++fn)
#pragma unroll
            for (int fm = 0; fm < 4; ++fm) {
                acc[fm][fn] = __builtin_amdgcn_mfma_f32_16x16x32_bf16(ah[fm], bh[fn], acc[fm][fn], 0, 0, 0);
                acc[fm][fn] = __builtin_amdgcn_mfma_f32_16x16x32_bf16(ah[fm], bl[fn], acc[fm][fn], 0, 0, 0);
                acc[fm][fn] = __builtin_amdgcn_mfma_f32_16x16x32_bf16(al[fm], bh[fn], acc[fm][fn], 0, 0, 0);
            }

        // tile t+1 must be complete before next iter; keep t+2 in flight.
        if (t < 62) asm volatile("s_waitcnt vmcnt(6)" ::: "memory");
        else        asm volatile("s_waitcnt vmcnt(0)" ::: "memory");
        __builtin_amdgcn_s_barrier();
        asm volatile("" ::: "memory");
    }

    // epilogue: C/D layout col(n)=lane&15, row(m)=(lane>>4)*4+reg (m89-verified)
#pragma unroll
    for (int fm = 0; fm < 4; ++fm) {
        int mg = m0 + wm * 64 + fm * 16 + (lane >> 4) * 4;
        float4 bv = *(const float4*)(bias + mg);
#pragma unroll
        for (int fn = 0; fn < 2; ++fn) {
            int ng = n0 + wn * 32 + fn * 16 + (lane & 15);
            f32x4 o = acc[fm][fn];
            if (ng >= PIX) { o[0] += bv.x; o[1] += bv.y; o[2] += bv.z; o[3] += bv.w; }
            *(f32x4*)(out + (size_t)ng * CDIM + mg) = o;
        }
    }
}

// ---------------------------------------------------------------------------
// Qm[p][c] = mean over 7x7 window of Qfull pixel cols + Qfull[576] (pos0+bias)
// grid (NP, 2): c-halves; one float4/row/thread.
__global__ __launch_bounds__(256) void qmean_k(const float* __restrict__ Qfull, float* __restrict__ Qm) {
    int p = blockIdx.x;
    int i = p / WO, j = p % WO;
    int c = blockIdx.y * 1024 + threadIdx.x * 4;
    float4 s = make_float4(0.f, 0.f, 0.f, 0.f);
#pragma unroll 7
    for (int t = 0; t < 49; ++t) {
        int px = (i + t / 7) * WF + (j + t % 7);
        float4 v = *(const float4*)(Qfull + (size_t)px * CDIM + c);
        s.x += v.x; s.y += v.y; s.z += v.z; s.w += v.w;
    }
    float4 p0 = *(const float4*)(Qfull + (size_t)PIX * CDIM + c);
    float4 r;
    r.x = s.x * (1.f / 49.f) + p0.x;
    r.y = s.y * (1.f / 49.f) + p0.y;
    r.z = s.z * (1.f / 49.f) + p0.z;
    r.w = s.w * (1.f / 49.f) + p0.w;
    *(float4*)(Qm + (size_t)p * CDIM + c) = r;
}

// ---------------------------------------------------------------------------
// TW[j][c] = (txt_j/||txt_j||) . out_w[:,c];  cconst[j] = (txt_j/||..||) . out_b
__global__ __launch_bounds__(256) void txtw_k(
    const float* __restrict__ txt, const float* __restrict__ out_w, const float* __restrict__ out_b,
    float* __restrict__ TW, float* __restrict__ cconst)
{
    __shared__ float ts[OUTD];
    __shared__ float red[256], redb[256];
    int j = blockIdx.x, cb = blockIdx.y, tid = threadIdx.x;

    float n2 = 0.f, db = 0.f;
    for (int o = tid; o < OUTD; o += 256) {
        float tv = txt[(size_t)j * OUTD + o];
        ts[o] = tv;
        n2 += tv * tv;
        db += tv * out_b[o];
    }
    red[tid] = n2; redb[tid] = db;
    __syncthreads();
    for (int s = 128; s > 0; s >>= 1) {
        if (tid < s) { red[tid] += red[tid + s]; redb[tid] += redb[tid + s]; }
        __syncthreads();
    }
    float inv = 1.f / sqrtf(red[0]);

    int c = cb * 256 + tid;
    float acc = 0.f;
    for (int o = 0; o < OUTD; ++o)
        acc += ts[o] * out_w[(size_t)o * CDIM + c];
    TW[(size_t)j * CDIM + c] = acc * inv;
    if (cb == 0 && tid == 0) cconst[j] = redb[0] * inv;
}

// ---------------------------------------------------------------------------
// TV[col][h*NTXT+j] = sum_d TW[j][h*64+d] * V[col][h*64+d]
__global__ __launch_bounds__(256) void tv_k(
    const float* __restrict__ TW, const float* __restrict__ Vbuf, float* __restrict__ TV)
{
    __shared__ float TWs[NTXT * HD];
    __shared__ float Vs[8 * HD];
    int cg = blockIdx.x, h = blockIdx.y, tid = threadIdx.x;
    int c0 = cg * 8;

    for (int idx = tid; idx < NTXT * HD; idx += 256) {
        int j = idx / HD, d = idx % HD;
        TWs[idx] = TW[(size_t)j * CDIM + h * HD + d];
    }
    for (int idx = tid; idx < 8 * HD; idx += 256) {
        int c = idx / HD, d = idx % HD;
        int col = c0 + c;
        Vs[idx] = (col < NKV) ? Vbuf[(size_t)col * CDIM + h * HD + d] : 0.f;
    }
    __syncthreads();

    for (int o = tid; o < 8 * NTXT; o += 256) {
        int c = o / NTXT, j = o % NTXT;
        int col = c0 + c;
        if (col >= NKV) continue;
        float acc = 0.f;
#pragma unroll
        for (int d = 0; d < HD; d += 4) {
            float4 tw = *(const float4*)&TWs[j * HD + d];
            float4 vv = *(const float4*)&Vs[c * HD + d];
            acc += tw.x * vv.x + tw.y * vv.y + tw.z * vv.z + tw.w * vv.w;
        }
        TV[(size_t)col * HJ + h * NTXT + j] = acc;
    }
}

// ---------------------------------------------------------------------------
// Fused per-(patch, 8-head-slice) scores + softmax + folded pooling.
// grid (NP, 4), block 384. Writes pooledHJ[p][o] for o in [s*360, s*360+360).
__global__ __launch_bounds__(384) void attn_fused_k(
    const float* __restrict__ Kbuf, const float* __restrict__ Qm,
    const float* __restrict__ TV, float* __restrict__ pooledHJ)
{
    __shared__ float qs[8 * HD];       // 512: q slice for 8 heads
    __shared__ float scf[8][NTOK];     // feature scores -> probs after softmax
    __shared__ float scp[8][NTOK];     // pos scores -> combined scores
    __shared__ int win[49];            // window pixel indices

    int p = blockIdx.x, s = blockIdx.y;
    int h0 = s * 8;
    int pi = p / WO, pj = p % WO;
    int tid = threadIdx.x;

    if (tid < 128)
        *(float4*)&qs[tid * 4] = *(const float4*)(Qm + (size_t)p * CDIM + h0 * HD + tid * 4);
    if (tid < 49)
        win[tid] = (pi + tid / 7) * WF + (pj + tid % 7);
    __syncthreads();

    // feature scores: 8 heads x 49 tokens
    for (int pair = tid; pair < 8 * 49; pair += 384) {
        int h = pair / 49, t = pair % 49 + 1;
        const float* kb = Kbuf + (size_t)win[t - 1] * CDIM + (h0 + h) * HD;
        float dot = 0.f;
#pragma unroll
        for (int d = 0; d < HD; d += 4) {
            float4 qv = *(const float4*)&qs[h * HD + d];
            float4 kv = *(const float4*)&kb[d];
            dot += qv.x * kv.x + qv.y * kv.y + qv.z * kv.z + qv.w * kv.w;
        }
        scf[h][t] = dot;
    }
    // pos scores: 8 heads x 50 tokens
    for (int pair = tid; pair < 8 * NTOK; pair += 384) {
        int h = pair / NTOK, t = pair % NTOK;
        const float* kp = Kbuf + (size_t)(PIX + t) * CDIM + (h0 + h) * HD;
        float dot = 0.f;
#pragma unroll
        for (int d = 0; d < HD; d += 4) {
            float4 qv = *(const float4*)&qs[h * HD + d];
            float4 kv = *(const float4*)&kp[d];
            dot += qv.x * kv.x + qv.y * kv.y + qv.z * kv.z + qv.w * kv.w;
        }
        scp[h][t] = dot;
    }
    __syncthreads();

    // softmax per head; mean-token feature part = mean of scf[1..49]
    if (tid < 8) {
        int h = tid;
        float sF = 0.f;
        for (int t = 1; t < NTOK; ++t) sF += scf[h][t];
        scf[h][0] = sF * (1.f / 49.f);
        float m = -1e30f;
        for (int t = 0; t < NTOK; ++t) {
            float sc = (scf[h][t] + scp[h][t]) * 0.125f;
            scp[h][t] = sc;
            m = fmaxf(m, sc);
        }
        float ssum = 0.f;
        for (int t = 0; t < NTOK; ++t) { float e = expf(scp[h][t] - m); scf[h][t] = e; ssum += e; }
        float inv = 1.f / ssum;
        for (int t = 0; t < NTOK; ++t) scf[h][t] *= inv;
    }
    __syncthreads();

    // folded pooling for this slice's o-window (contiguous, coalesced)
    if (tid < 360) {
        int o = s * 360 + tid;
        int hloc = tid / 45;
        const float* apr = &scf[hloc][0];
        float lacc = 0.f, macc = 0.f;
#pragma unroll 7
        for (int t = 1; t < NTOK; ++t) {
            float a = apr[t];
            float v1 = TV[(size_t)win[t - 1] * HJ + o];
            float v2 = TV[(size_t)(PIX + t) * HJ + o];
            lacc += a * (v1 + v2);
            macc += v1;
        }
        float a0 = apr[0];
        lacc += a0 * (macc * (1.f / 49.f) + TV[(size_t)PIX * HJ + o]);
        pooledHJ[(size_t)p * HJ + o] = lacc;
    }
}

// ---------------------------------------------------------------------------
// finish: reduce pooledHJ over heads, add cconst, argmax -> bucket
__global__ __launch_bounds__(64) void finish_k(const float* __restrict__ pooledHJ,
                                               const float* __restrict__ cconst,
                                               int* __restrict__ bucket) {
    __shared__ float lg[NTXT];
    int p = blockIdx.x, lane = threadIdx.x;
    if (lane < NTXT) {
        float s = cconst[lane];
        const float* row = pooledHJ + (size_t)p * HJ;
#pragma unroll 8
        for (int h = 0; h < NHEAD; ++h) s += row[h * NTXT + lane];
        lg[lane] = s;
    }
    __syncthreads();
    if (lane == 0) {
        float best = lg[0]; int bi = 0;
        for (int j2 = 1; j2 < NTXT; ++j2)
            if (lg[j2] > best) { best = lg[j2]; bi = j2; }
        int bk = 0;
        const int bounds[5] = {8, 15, 22, 29, 36};
#pragma unroll
        for (int u = 0; u < 5; ++u) bk += (bi >= bounds[u]) ? 1 : 0;
        bucket[p] = bk;
    }
}

// ---------------------------------------------------------------------------
__global__ void votes_k(const int* __restrict__ bucket, float* __restrict__ maxval) {
    __shared__ int bk[NP];
    int tid = threadIdx.x;
    if (tid < NP) bk[tid] = bucket[tid];
    __syncthreads();
    if (tid < PIX) {
        int y = tid / WF, x = tid % WF;
        int cnt[6] = {0, 0, 0, 0, 0, 0};
        int i0 = (y - 6 < 0) ? 0 : y - 6;
        int i1 = (y > HO - 1) ? HO - 1 : y;
        int j0 = (x - 6 < 0) ? 0 : x - 6;
        int j1 = (x > WO - 1) ? WO - 1 : x;
        for (int i = i0; i <= i1; ++i)
            for (int j = j0; j <= j1; ++j)
                cnt[bk[i * WO + j]]++;
        int best = cnt[0], bi = 0;
#pragma unroll
        for (int ch = 1; ch < 6; ++ch)
            if (cnt[ch] > best) { best = cnt[ch]; bi = ch; }
        maxval[tid] = (bi > 0) ? 0.044194173824159216f : 0.f;
    }
}

__global__ void fill_k(const float* __restrict__ maxval, float* __restrict__ out) {
    int idx = blockIdx.x * 256 + threadIdx.x;
    const int HALF = OUTD * PIX;
    if (idx >= 2 * HALF) return;
    out[idx] = (idx < HALF) ? 0.f : maxval[idx % PIX];
}

// ---------------------------------------------------------------------------
extern "C" void kernel_launch(void* const* d_in, const int* in_sizes, int n_in,
                              void* d_out, int out_size, void* d_ws, size_t ws_size,
                              hipStream_t stream) {
    const float* imgf = (const float*)d_in[0];
    const float* txt  = (const float*)d_in[1];
    const float* pos  = (const float*)d_in[2];
    const float* q_w  = (const float*)d_in[3];
    const float* q_b  = (const float*)d_in[4];
    const float* k_w  = (const float*)d_in[5];
    const float* k_b  = (const float*)d_in[6];
    const float* v_w  = (const float*)d_in[7];
    const float* v_b  = (const float*)d_in[8];
    const float* o_w  = (const float*)d_in[9];
    const float* o_b  = (const float*)d_in[10];

    const float* feat1 = imgf + (size_t)1 * CDIM * PIX;   // only batch B-1=1 matters

    float* ws = (float*)d_ws;
    float* Kbuf  = ws;                                   // 640*2048
    float* Vbuf  = Kbuf + (size_t)NROWS * CDIM;
    float* Qfull = Vbuf + (size_t)NROWS * CDIM;
    float* Qm    = Qfull + (size_t)NROWS * CDIM;         // 324*2048
    float* TW    = Qm + (size_t)NP * CDIM;               // 45*2048
    float* cconst = TW + (size_t)NTXT * CDIM;            // 64
    float* TV    = cconst + 64;                          // 626*1440
    float* pooledHJ = TV + (size_t)NKV * HJ;             // 324*1440
    int*   bucket = (int*)(pooledHJ + (size_t)NP * HJ);  // 324
    float* maxval = (float*)(bucket + NP);               // 576
    size_t foff = (size_t)(maxval + 576 - ws);
    foff = (foff + 3) & ~(size_t)3;                      // 16B align
    ushort* WhK = (ushort*)(ws + foff);                  // each 2048*2048
    ushort* WlK = WhK + (size_t)CDIM * CDIM;
    ushort* WhV = WlK + (size_t)CDIM * CDIM;
    ushort* WlV = WhV + (size_t)CDIM * CDIM;
    ushort* WhQ = WlV + (size_t)CDIM * CDIM;
    ushort* WlQ = WhQ + (size_t)CDIM * CDIM;
    ushort* Xh  = WlQ + (size_t)CDIM * CDIM;             // 640*2048
    ushort* Xl  = Xh + (size_t)NROWS * CDIM;

    split_w_k<<<dim3(12288), dim3(256), 0, stream>>>(k_w, v_w, q_w, WhK, WlK, WhV, WlV, WhQ, WlQ);
    split_xt_k<<<dim3(9, 32), dim3(256), 0, stream>>>(feat1, Xh, Xl);
    split_pos_k<<<dim3(128), dim3(256), 0, stream>>>(pos, Xh, Xl);
    gemm_bf16_k<<<dim3(16, 10, 3), dim3(256), 0, stream>>>(WhK, WlK, WhV, WlV, WhQ, WlQ,
                                                           Xh, Xl, k_b, v_b, q_b, Kbuf, Vbuf, Qfull);
    qmean_k<<<dim3(NP, 2), dim3(256), 0, stream>>>(Qfull, Qm);
    txtw_k<<<dim3(NTXT, 8), dim3(256), 0, stream>>>(txt, o_w, o_b, TW, cconst);
    tv_k<<<dim3(79, 32), dim3(256), 0, stream>>>(TW, Vbuf, TV);
    attn_fused_k<<<dim3(NP, 4), dim3(384), 0, stream>>>(Kbuf, Qm, TV, pooledHJ);
    finish_k<<<dim3(NP), dim3(64), 0, stream>>>(pooledHJ, cconst, bucket);
    votes_k<<<dim3(1), dim3(576), 0, stream>>>(bucket, maxval);
    fill_k<<<dim3(2304), dim3(256), 0, stream>>>(maxval, (float*)d_out);
}

// Round 7
// 242.062 us; speedup vs baseline: 1.0921x; 1.0921x over previous
//
#include <hip/hip_runtime.h>
#include <math.h>

#define CDIM 2048
#define HF 24
#define WF 24
#define PIX 576
#define HO 18
#define WO 18
#define NP 324
#define NHEAD 32
#define HD 64
#define NTOK 50
#define NTXT 45
#define OUTD 512
#define NKV 626
#define HJ (NHEAD * NTXT)   // 1440
#define NROWS 640           // padded B rows: 576 pixels + 50 pos + 14 zero

typedef __attribute__((ext_vector_type(8))) short short8;
typedef __attribute__((ext_vector_type(4))) float f32x4;
typedef __attribute__((address_space(1))) const void as1c_void;
typedef __attribute__((address_space(3))) void as3_void;

__device__ inline unsigned bf16rn(float x) {
    unsigned u = __float_as_uint(x);
    return (u + 0x7FFFu + ((u >> 16) & 1u)) >> 16;
}
__device__ inline float bf16tof(unsigned h) { return __uint_as_float(h << 16); }

// Fragment-tile global layout (ushort element offset):
// tile (row>>4, k>>5) is 512 contiguous ushorts (1KB); within it lane = chunk*16+lrow
// holds 8 k-elems. Matches the GEMM's LDS fragment layout exactly, so
// global_load_lds reads are single contiguous 1KB bursts (lane*16B).
__device__ inline size_t frag_off(int row, int k) {
    return (size_t)(((row >> 4) * 64 + (k >> 5)) * 512)
         + (size_t)(((k & 31) >> 3) * 128 + (row & 15) * 8 + (k & 7));
}

// ---------------------------------------------------------------------------
// Split the 3 weight matrices into hi/lo bf16, fragment-tile layout.
__global__ void split_w_k(const float* __restrict__ kw, const float* __restrict__ vw, const float* __restrict__ qw,
                          ushort* __restrict__ WhK, ushort* __restrict__ WlK,
                          ushort* __restrict__ WhV, ushort* __restrict__ WlV,
                          ushort* __restrict__ WhQ, ushort* __restrict__ WlQ) {
    int g = blockIdx.x * 256 + threadIdx.x;      // 3 * 1048576 threads, 4 elems each
    int sel = g >> 20;
    int off = (g & 1048575) * 4;                 // flat elem offset = m*2048 + k0, k0%4==0
    const float* src = sel == 0 ? kw : sel == 1 ? vw : qw;
    ushort* dh = sel == 0 ? WhK : sel == 1 ? WhV : WhQ;
    ushort* dl = sel == 0 ? WlK : sel == 1 ? WlV : WlQ;
    float4 v = *(const float4*)(src + off);
    float xs[4] = {v.x, v.y, v.z, v.w};
    ushort h[4], l[4];
#pragma unroll
    for (int i = 0; i < 4; ++i) {
        unsigned hh = bf16rn(xs[i]);
        h[i] = (ushort)hh;
        l[i] = (ushort)bf16rn(xs[i] - bf16tof(hh));
    }
    int m = off >> 11, k0 = off & 2047;
    size_t fo = frag_off(m, k0);                 // k0%4==0 -> 4 consecutive ushorts, 8B aligned
    *(ushort4*)(dh + fo) = make_ushort4(h[0], h[1], h[2], h[3]);
    *(ushort4*)(dl + fo) = make_ushort4(l[0], l[1], l[2], l[3]);
}

// ---------------------------------------------------------------------------
// Transpose+split feat1 [2048][576] f32 -> Xh/Xl fragment-tile layout, rows 0..575.
__global__ __launch_bounds__(256) void split_xt_k(const float* __restrict__ feat1,
                                                  ushort* __restrict__ Xh, ushort* __restrict__ Xl) {
    __shared__ float tile[64][65];
    int n0 = blockIdx.x * 64, c0 = blockIdx.y * 64, tid = threadIdx.x;
#pragma unroll
    for (int i = 0; i < 16; ++i) {
        int idx = tid + i * 256;
        int cc = idx >> 6, nn = idx & 63;
        tile[cc][nn] = feat1[(size_t)(c0 + cc) * PIX + n0 + nn];
    }
    __syncthreads();
#pragma unroll
    for (int i = 0; i < 16; ++i) {
        int idx = tid + i * 256;
        int nn = idx >> 6, cc = idx & 63;
        float x = tile[cc][nn];
        unsigned hh = bf16rn(x);
        size_t fo = frag_off(n0 + nn, c0 + cc);
        Xh[fo] = (ushort)hh;
        Xl[fo] = (ushort)bf16rn(x - bf16tof(hh));
    }
}

// ---------------------------------------------------------------------------
// Rows 576..639 of Xh/Xl: pos tokens (split) for r<50, zeros for pad rows.
__global__ void split_pos_k(const float* __restrict__ pos,
                            ushort* __restrict__ Xh, ushort* __restrict__ Xl) {
    int g = blockIdx.x * 256 + threadIdx.x;     // 32768 threads, 4 elems each
    int r = g >> 9;                              // 0..63
    int c = (g & 511) * 4;
    float4 v = make_float4(0.f, 0.f, 0.f, 0.f);
    if (r < 50) v = *(const float4*)(pos + (size_t)r * CDIM + c);
    float xs[4] = {v.x, v.y, v.z, v.w};
    ushort h[4], l[4];
#pragma unroll
    for (int i = 0; i < 4; ++i) {
        unsigned hh = bf16rn(xs[i]);
        h[i] = (ushort)hh;
        l[i] = (ushort)bf16rn(xs[i] - bf16tof(hh));
    }
    size_t fo = frag_off(576 + r, c);
    *(ushort4*)(Xh + fo) = make_ushort4(h[0], h[1], h[2], h[3]);
    *(ushort4*)(Xl + fo) = make_ushort4(l[0], l[1], l[2], l[3]);
}

// ---------------------------------------------------------------------------
// Split-bf16 MFMA GEMM, 3-buffer depth-2 pipeline, coalesced frag-tile staging:
//   out[n][m] = sum_k W[m][k]*X[n][k]
// 3 products: WhXh + WhXl + WlXh. Tile 128m x 64n, BK=32, 4 waves (2x2, wave=64x32).
// Each slot load = one contiguous 1KB burst (lane*16B) -> single VMEM segment.
#define BUFB 24576
__global__ __launch_bounds__(256, 2) void gemm_bf16_k(
    const ushort* __restrict__ WhK, const ushort* __restrict__ WlK,
    const ushort* __restrict__ WhV, const ushort* __restrict__ WlV,
    const ushort* __restrict__ WhQ, const ushort* __restrict__ WlQ,
    const ushort* __restrict__ Xh, const ushort* __restrict__ Xl,
    const float* __restrict__ k_b, const float* __restrict__ v_b, const float* __restrict__ q_b,
    float* __restrict__ Kbuf, float* __restrict__ Vbuf, float* __restrict__ Qfull)
{
    __shared__ char smem[3 * BUFB];   // 72 KB: 3 rotating tile buffers
    int z = blockIdx.z;
    const ushort* Wh = z == 0 ? WhK : z == 1 ? WhV : WhQ;
    const ushort* Wl = z == 0 ? WlK : z == 1 ? WlV : WlQ;
    const float* bias = z == 0 ? k_b : z == 1 ? v_b : q_b;
    float* out = z == 0 ? Kbuf : z == 1 ? Vbuf : Qfull;
    int m0 = blockIdx.x * 128, n0 = blockIdx.y * 64;

    int tid = threadIdx.x, wid = tid >> 6, lane = tid & 63;
    int wm = wid >> 1, wn = wid & 1;

    // per-wave staging: 24 slot-loads/block, 6 per wave; each slot is a 16-row
    // fragment block whose k-tile t lives at base + t*1024 (contiguous 1KB).
    const char* gsrc[6];
    int ldsoff[6];
#pragma unroll
    for (int i = 0; i < 6; ++i) {
        int g = wid * 6 + i;
        const ushort* src; int r16; int off;
        if (g < 8)       { src = Wh; r16 = (m0 >> 4) + g;        off = g * 1024; }
        else if (g < 16) { src = Wl; r16 = (m0 >> 4) + (g - 8);  off = 8192 + (g - 8) * 1024; }
        else if (g < 20) { src = Xh; r16 = (n0 >> 4) + (g - 16); off = 16384 + (g - 16) * 1024; }
        else             { src = Xl; r16 = (n0 >> 4) + (g - 20); off = 20480 + (g - 20) * 1024; }
        gsrc[i] = (const char*)src + ((size_t)r16 * 64 * 1024) + lane * 16;
        ldsoff[i] = off;
    }

    f32x4 acc[4][2];
#pragma unroll
    for (int a = 0; a < 4; ++a)
#pragma unroll
        for (int b = 0; b < 2; ++b) acc[a][b] = (f32x4)0.f;

    // prologue: stage tiles 0 and 1 into buffers 0 and 1
#pragma unroll
    for (int i = 0; i < 6; ++i)
        __builtin_amdgcn_global_load_lds((as1c_void*)(gsrc[i]),
                                         (as3_void*)(smem + ldsoff[i]), 16, 0, 0);
#pragma unroll
    for (int i = 0; i < 6; ++i)
        __builtin_amdgcn_global_load_lds((as1c_void*)(gsrc[i] + 1024),
                                         (as3_void*)(smem + BUFB + ldsoff[i]), 16, 0, 0);
    asm volatile("s_waitcnt vmcnt(6)" ::: "memory");   // tile 0 complete
    __builtin_amdgcn_s_barrier();
    asm volatile("" ::: "memory");

    for (int t = 0; t < 64; ++t) {
        char* rbuf = smem + (t % 3) * BUFB;
        // stage tile t+2 into the buffer freed by tile t-1 (barrier'd)
        if (t < 62) {
            char* wbuf = smem + ((t + 2) % 3) * BUFB;
#pragma unroll
            for (int i = 0; i < 6; ++i)
                __builtin_amdgcn_global_load_lds((as1c_void*)(gsrc[i] + (size_t)(t + 2) * 1024),
                                                 (as3_void*)(wbuf + ldsoff[i]), 16, 0, 0);
        }

        short8 ah[4], al[4];
#pragma unroll
        for (int fm = 0; fm < 4; ++fm) {
            int s = wm * 4 + fm;
            ah[fm] = *(const short8*)(rbuf + s * 1024 + lane * 16);
            al[fm] = *(const short8*)(rbuf + 8192 + s * 1024 + lane * 16);
        }
        short8 bh[2], bl[2];
#pragma unroll
        for (int fn = 0; fn < 2; ++fn) {
            int s = wn * 2 + fn;
            bh[fn] = *(const short8*)(rbuf + 16384 + s * 1024 + lane * 16);
            bl[fn] = *(const short8*)(rbuf + 20480 + s * 1024 + lane * 16);
        }
#pragma unroll
        for (int fn = 0; fn < 2; ++fn)
#pragma unroll
            for (int fm = 0; fm < 4; ++fm) {
                acc[fm][fn] = __builtin_amdgcn_mfma_f32_16x16x32_bf16(ah[fm], bh[fn], acc[fm][fn], 0, 0, 0);
                acc[fm][fn] = __builtin_amdgcn_mfma_f32_16x16x32_bf16(ah[fm], bl[fn], acc[fm][fn], 0, 0, 0);
                acc[fm][fn] = __builtin_amdgcn_mfma_f32_16x16x32_bf16(al[fm], bh[fn], acc[fm][fn], 0, 0, 0);
            }

        // tile t+1 must be complete before next iter; keep t+2 in flight.
        if (t < 62) asm volatile("s_waitcnt vmcnt(6)" ::: "memory");
        else        asm volatile("s_waitcnt vmcnt(0)" ::: "memory");
        __builtin_amdgcn_s_barrier();
        asm volatile("" ::: "memory");
    }

    // epilogue: C/D layout col(n)=lane&15, row(m)=(lane>>4)*4+reg (m89-verified)
#pragma unroll
    for (int fm = 0; fm < 4; ++fm) {
        int mg = m0 + wm * 64 + fm * 16 + (lane >> 4) * 4;
        float4 bv = *(const float4*)(bias + mg);
#pragma unroll
        for (int fn = 0; fn < 2; ++fn) {
            int ng = n0 + wn * 32 + fn * 16 + (lane & 15);
            f32x4 o = acc[fm][fn];
            if (ng >= PIX) { o[0] += bv.x; o[1] += bv.y; o[2] += bv.z; o[3] += bv.w; }
            *(f32x4*)(out + (size_t)ng * CDIM + mg) = o;
        }
    }
}

// ---------------------------------------------------------------------------
// Qm[p][c] = mean over 7x7 window of Qfull pixel cols + Qfull[576] (pos0+bias)
// grid (NP, 2): c-halves; one float4/row/thread.
__global__ __launch_bounds__(256) void qmean_k(const float* __restrict__ Qfull, float* __restrict__ Qm) {
    int p = blockIdx.x;
    int i = p / WO, j = p % WO;
    int c = blockIdx.y * 1024 + threadIdx.x * 4;
    float4 s = make_float4(0.f, 0.f, 0.f, 0.f);
#pragma unroll 7
    for (int t = 0; t < 49; ++t) {
        int px = (i + t / 7) * WF + (j + t % 7);
        float4 v = *(const float4*)(Qfull + (size_t)px * CDIM + c);
        s.x += v.x; s.y += v.y; s.z += v.z; s.w += v.w;
    }
    float4 p0 = *(const float4*)(Qfull + (size_t)PIX * CDIM + c);
    float4 r;
    r.x = s.x * (1.f / 49.f) + p0.x;
    r.y = s.y * (1.f / 49.f) + p0.y;
    r.z = s.z * (1.f / 49.f) + p0.z;
    r.w = s.w * (1.f / 49.f) + p0.w;
    *(float4*)(Qm + (size_t)p * CDIM + c) = r;
}

// ---------------------------------------------------------------------------
// TW[j][c] = (txt_j/||txt_j||) . out_w[:,c];  cconst[j] = (txt_j/||..||) . out_b
__global__ __launch_bounds__(256) void txtw_k(
    const float* __restrict__ txt, const float* __restrict__ out_w, const float* __restrict__ out_b,
    float* __restrict__ TW, float* __restrict__ cconst)
{
    __shared__ float ts[OUTD];
    __shared__ float red[256], redb[256];
    int j = blockIdx.x, cb = blockIdx.y, tid = threadIdx.x;

    float n2 = 0.f, db = 0.f;
    for (int o = tid; o < OUTD; o += 256) {
        float tv = txt[(size_t)j * OUTD + o];
        ts[o] = tv;
        n2 += tv * tv;
        db += tv * out_b[o];
    }
    red[tid] = n2; redb[tid] = db;
    __syncthreads();
    for (int s = 128; s > 0; s >>= 1) {
        if (tid < s) { red[tid] += red[tid + s]; redb[tid] += redb[tid + s]; }
        __syncthreads();
    }
    float inv = 1.f / sqrtf(red[0]);

    int c = cb * 256 + tid;
    float acc = 0.f;
    for (int o = 0; o < OUTD; ++o)
        acc += ts[o] * out_w[(size_t)o * CDIM + c];
    TW[(size_t)j * CDIM + c] = acc * inv;
    if (cb == 0 && tid == 0) cconst[j] = redb[0] * inv;
}

// ---------------------------------------------------------------------------
// TV[col][h*NTXT+j] = sum_d TW[j][h*64+d] * V[col][h*64+d]
__global__ __launch_bounds__(256) void tv_k(
    const float* __restrict__ TW, const float* __restrict__ Vbuf, float* __restrict__ TV)
{
    __shared__ float TWs[NTXT * HD];
    __shared__ float Vs[8 * HD];
    int cg = blockIdx.x, h = blockIdx.y, tid = threadIdx.x;
    int c0 = cg * 8;

    for (int idx = tid; idx < NTXT * HD; idx += 256) {
        int j = idx / HD, d = idx % HD;
        TWs[idx] = TW[(size_t)j * CDIM + h * HD + d];
    }
    for (int idx = tid; idx < 8 * HD; idx += 256) {
        int c = idx / HD, d = idx % HD;
        int col = c0 + c;
        Vs[idx] = (col < NKV) ? Vbuf[(size_t)col * CDIM + h * HD + d] : 0.f;
    }
    __syncthreads();

    for (int o = tid; o < 8 * NTXT; o += 256) {
        int c = o / NTXT, j = o % NTXT;
        int col = c0 + c;
        if (col >= NKV) continue;
        float acc = 0.f;
#pragma unroll
        for (int d = 0; d < HD; d += 4) {
            float4 tw = *(const float4*)&TWs[j * HD + d];
            float4 vv = *(const float4*)&Vs[c * HD + d];
            acc += tw.x * vv.x + tw.y * vv.y + tw.z * vv.z + tw.w * vv.w;
        }
        TV[(size_t)col * HJ + h * NTXT + j] = acc;
    }
}

// ---------------------------------------------------------------------------
// Fused per-(patch, 8-head-slice) scores + softmax + folded pooling.
// grid (NP, 4), block 384. Writes pooledHJ[p][o] for o in [s*360, s*360+360).
__global__ __launch_bounds__(384) void attn_fused_k(
    const float* __restrict__ Kbuf, const float* __restrict__ Qm,
    const float* __restrict__ TV, float* __restrict__ pooledHJ)
{
    __shared__ float qs[8 * HD];       // 512: q slice for 8 heads
    __shared__ float scf[8][NTOK];     // feature scores -> probs after softmax
    __shared__ float scp[8][NTOK];     // pos scores -> combined scores
    __shared__ int win[49];            // window pixel indices

    int p = blockIdx.x, s = blockIdx.y;
    int h0 = s * 8;
    int pi = p / WO, pj = p % WO;
    int tid = threadIdx.x;

    if (tid < 128)
        *(float4*)&qs[tid * 4] = *(const float4*)(Qm + (size_t)p * CDIM + h0 * HD + tid * 4);
    if (tid < 49)
        win[tid] = (pi + tid / 7) * WF + (pj + tid % 7);
    __syncthreads();

    // feature scores: 8 heads x 49 tokens
    for (int pair = tid; pair < 8 * 49; pair += 384) {
        int h = pair / 49, t = pair % 49 + 1;
        const float* kb = Kbuf + (size_t)win[t - 1] * CDIM + (h0 + h) * HD;
        float dot = 0.f;
#pragma unroll
        for (int d = 0; d < HD; d += 4) {
            float4 qv = *(const float4*)&qs[h * HD + d];
            float4 kv = *(const float4*)&kb[d];
            dot += qv.x * kv.x + qv.y * kv.y + qv.z * kv.z + qv.w * kv.w;
        }
        scf[h][t] = dot;
    }
    // pos scores: 8 heads x 50 tokens
    for (int pair = tid; pair < 8 * NTOK; pair += 384) {
        int h = pair / NTOK, t = pair % NTOK;
        const float* kp = Kbuf + (size_t)(PIX + t) * CDIM + (h0 + h) * HD;
        float dot = 0.f;
#pragma unroll
        for (int d = 0; d < HD; d += 4) {
            float4 qv = *(const float4*)&qs[h * HD + d];
            float4 kv = *(const float4*)&kp[d];
            dot += qv.x * kv.x + qv.y * kv.y + qv.z * kv.z + qv.w * kv.w;
        }
        scp[h][t] = dot;
    }
    __syncthreads();

    // softmax per head; mean-token feature part = mean of scf[1..49]
    if (tid < 8) {
        int h = tid;
        float sF = 0.f;
        for (int t = 1; t < NTOK; ++t) sF += scf[h][t];
        scf[h][0] = sF * (1.f / 49.f);
        float m = -1e30f;
        for (int t = 0; t < NTOK; ++t) {
            float sc = (scf[h][t] + scp[h][t]) * 0.125f;
            scp[h][t] = sc;
            m = fmaxf(m, sc);
        }
        float ssum = 0.f;
        for (int t = 0; t < NTOK; ++t) { float e = expf(scp[h][t] - m); scf[h][t] = e; ssum += e; }
        float inv = 1.f / ssum;
        for (int t = 0; t < NTOK; ++t) scf[h][t] *= inv;
    }
    __syncthreads();

    // folded pooling for this slice's o-window (contiguous, coalesced)
    if (tid < 360) {
        int o = s * 360 + tid;
        int hloc = tid / 45;
        const float* apr = &scf[hloc][0];
        float lacc = 0.f, macc = 0.f;
#pragma unroll 7
        for (int t = 1; t < NTOK; ++t) {
            float a = apr[t];
            float v1 = TV[(size_t)win[t - 1] * HJ + o];
            float v2 = TV[(size_t)(PIX + t) * HJ + o];
            lacc += a * (v1 + v2);
            macc += v1;
        }
        float a0 = apr[0];
        lacc += a0 * (macc * (1.f / 49.f) + TV[(size_t)PIX * HJ + o]);
        pooledHJ[(size_t)p * HJ + o] = lacc;
    }
}

// ---------------------------------------------------------------------------
// finish: reduce pooledHJ over heads, add cconst, argmax -> bucket
__global__ __launch_bounds__(64) void finish_k(const float* __restrict__ pooledHJ,
                                               const float* __restrict__ cconst,
                                               int* __restrict__ bucket) {
    __shared__ float lg[NTXT];
    int p = blockIdx.x, lane = threadIdx.x;
    if (lane < NTXT) {
        float s = cconst[lane];
        const float* row = pooledHJ + (size_t)p * HJ;
#pragma unroll 8
        for (int h = 0; h < NHEAD; ++h) s += row[h * NTXT + lane];
        lg[lane] = s;
    }
    __syncthreads();
    if (lane == 0) {
        float best = lg[0]; int bi = 0;
        for (int j2 = 1; j2 < NTXT; ++j2)
            if (lg[j2] > best) { best = lg[j2]; bi = j2; }
        int bk = 0;
        const int bounds[5] = {8, 15, 22, 29, 36};
#pragma unroll
        for (int u = 0; u < 5; ++u) bk += (bi >= bounds[u]) ? 1 : 0;
        bucket[p] = bk;
    }
}

// ---------------------------------------------------------------------------
__global__ void votes_k(const int* __restrict__ bucket, float* __restrict__ maxval) {
    __shared__ int bk[NP];
    int tid = threadIdx.x;
    if (tid < NP) bk[tid] = bucket[tid];
    __syncthreads();
    if (tid < PIX) {
        int y = tid / WF, x = tid % WF;
        int cnt[6] = {0, 0, 0, 0, 0, 0};
        int i0 = (y - 6 < 0) ? 0 : y - 6;
        int i1 = (y > HO - 1) ? HO - 1 : y;
        int j0 = (x - 6 < 0) ? 0 : x - 6;
        int j1 = (x > WO - 1) ? WO - 1 : x;
        for (int i = i0; i <= i1; ++i)
            for (int j = j0; j <= j1; ++j)
                cnt[bk[i * WO + j]]++;
        int best = cnt[0], bi = 0;
#pragma unroll
        for (int ch = 1; ch < 6; ++ch)
            if (cnt[ch] > best) { best = cnt[ch]; bi = ch; }
        maxval[tid] = (bi > 0) ? 0.044194173824159216f : 0.f;
    }
}

__global__ void fill_k(const float* __restrict__ maxval, float* __restrict__ out) {
    int idx = blockIdx.x * 256 + threadIdx.x;
    const int HALF = OUTD * PIX;
    if (idx >= 2 * HALF) return;
    out[idx] = (idx < HALF) ? 0.f : maxval[idx % PIX];
}

// ---------------------------------------------------------------------------
extern "C" void kernel_launch(void* const* d_in, const int* in_sizes, int n_in,
                              void* d_out, int out_size, void* d_ws, size_t ws_size,
                              hipStream_t stream) {
    const float* imgf = (const float*)d_in[0];
    const float* txt  = (const float*)d_in[1];
    const float* pos  = (const float*)d_in[2];
    const float* q_w  = (const float*)d_in[3];
    const float* q_b  = (const float*)d_in[4];
    const float* k_w  = (const float*)d_in[5];
    const float* k_b  = (const float*)d_in[6];
    const float* v_w  = (const float*)d_in[7];
    const float* v_b  = (const float*)d_in[8];
    const float* o_w  = (const float*)d_in[9];
    const float* o_b  = (const float*)d_in[10];

    const float* feat1 = imgf + (size_t)1 * CDIM * PIX;   // only batch B-1=1 matters

    float* ws = (float*)d_ws;
    float* Kbuf  = ws;                                   // 640*2048
    float* Vbuf  = Kbuf + (size_t)NROWS * CDIM;
    float* Qfull = Vbuf + (size_t)NROWS * CDIM;
    float* Qm    = Qfull + (size_t)NROWS * CDIM;         // 324*2048
    float* TW    = Qm + (size_t)NP * CDIM;               // 45*2048
    float* cconst = TW + (size_t)NTXT * CDIM;            // 64
    float* TV    = cconst + 64;                          // 626*1440
    float* pooledHJ = TV + (size_t)NKV * HJ;             // 324*1440
    int*   bucket = (int*)(pooledHJ + (size_t)NP * HJ);  // 324
    float* maxval = (float*)(bucket + NP);               // 576
    size_t foff = (size_t)(maxval + 576 - ws);
    foff = (foff + 3) & ~(size_t)3;                      // 16B align
    ushort* WhK = (ushort*)(ws + foff);                  // each 2048*2048
    ushort* WlK = WhK + (size_t)CDIM * CDIM;
    ushort* WhV = WlK + (size_t)CDIM * CDIM;
    ushort* WlV = WhV + (size_t)CDIM * CDIM;
    ushort* WhQ = WlV + (size_t)CDIM * CDIM;
    ushort* WlQ = WhQ + (size_t)CDIM * CDIM;
    ushort* Xh  = WlQ + (size_t)CDIM * CDIM;             // 640*2048
    ushort* Xl  = Xh + (size_t)NROWS * CDIM;

    split_w_k<<<dim3(12288), dim3(256), 0, stream>>>(k_w, v_w, q_w, WhK, WlK, WhV, WlV, WhQ, WlQ);
    split_xt_k<<<dim3(9, 32), dim3(256), 0, stream>>>(feat1, Xh, Xl);
    split_pos_k<<<dim3(128), dim3(256), 0, stream>>>(pos, Xh, Xl);
    gemm_bf16_k<<<dim3(16, 10, 3), dim3(256), 0, stream>>>(WhK, WlK, WhV, WlV, WhQ, WlQ,
                                                           Xh, Xl, k_b, v_b, q_b, Kbuf, Vbuf, Qfull);
    qmean_k<<<dim3(NP, 2), dim3(256), 0, stream>>>(Qfull, Qm);
    txtw_k<<<dim3(NTXT, 8), dim3(256), 0, stream>>>(txt, o_w, o_b, TW, cconst);
    tv_k<<<dim3(79, 32), dim3(256), 0, stream>>>(TW, Vbuf, TV);
    attn_fused_k<<<dim3(NP, 4), dim3(384), 0, stream>>>(Kbuf, Qm, TV, pooledHJ);
    finish_k<<<dim3(NP), dim3(64), 0, stream>>>(pooledHJ, cconst, bucket);
    votes_k<<<dim3(1), dim3(576), 0, stream>>>(bucket, maxval);
    fill_k<<<dim3(2304), dim3(256), 0, stream>>>(maxval, (float*)d_out);
}

// Round 8
// 234.874 us; speedup vs baseline: 1.1255x; 1.0306x over previous
//
#include <hip/hip_runtime.h>
#include <math.h>

#define CDIM 2048
#define HF 24
#define WF 24
#define PIX 576
#define HO 18
#define WO 18
#define NP 324
#define NHEAD 32
#define HD 64
#define NTOK 50
#define NTXT 45
#define OUTD 512
#define NKV 626
#define HJ (NHEAD * NTXT)   // 1440
#define NROWS 640           // padded B rows: 576 pixels + 50 pos + 14 zero

typedef __attribute__((ext_vector_type(8))) short short8;
typedef __attribute__((ext_vector_type(4))) float f32x4;
typedef __attribute__((address_space(1))) const void as1c_void;
typedef __attribute__((address_space(3))) void as3_void;

__device__ inline unsigned bf16rn(float x) {
    unsigned u = __float_as_uint(x);
    return (u + 0x7FFFu + ((u >> 16) & 1u)) >> 16;
}
__device__ inline float bf16tof(unsigned h) { return __uint_as_float(h << 16); }

// Fragment-tile global layout (ushort element offset):
// tile (row>>4, k>>5) is 512 contiguous ushorts (1KB); within it lane = chunk*16+lrow
// holds 8 k-elems. Matches the GEMM's LDS fragment layout exactly, so
// global_load_lds reads are single contiguous 1KB bursts (lane*16B).
__device__ inline size_t frag_off(int row, int k) {
    return (size_t)(((row >> 4) * 64 + (k >> 5)) * 512)
         + (size_t)(((k & 31) >> 3) * 128 + (row & 15) * 8 + (k & 7));
}

// ---------------------------------------------------------------------------
// Split the 3 weight matrices into hi/lo bf16, fragment-tile layout.
__global__ void split_w_k(const float* __restrict__ kw, const float* __restrict__ vw, const float* __restrict__ qw,
                          ushort* __restrict__ WhK, ushort* __restrict__ WlK,
                          ushort* __restrict__ WhV, ushort* __restrict__ WlV,
                          ushort* __restrict__ WhQ, ushort* __restrict__ WlQ) {
    int g = blockIdx.x * 256 + threadIdx.x;      // 3 * 1048576 threads, 4 elems each
    int sel = g >> 20;
    int off = (g & 1048575) * 4;                 // flat elem offset = m*2048 + k0, k0%4==0
    const float* src = sel == 0 ? kw : sel == 1 ? vw : qw;
    ushort* dh = sel == 0 ? WhK : sel == 1 ? WhV : WhQ;
    ushort* dl = sel == 0 ? WlK : sel == 1 ? WlV : WlQ;
    float4 v = *(const float4*)(src + off);
    float xs[4] = {v.x, v.y, v.z, v.w};
    ushort h[4], l[4];
#pragma unroll
    for (int i = 0; i < 4; ++i) {
        unsigned hh = bf16rn(xs[i]);
        h[i] = (ushort)hh;
        l[i] = (ushort)bf16rn(xs[i] - bf16tof(hh));
    }
    int m = off >> 11, k0 = off & 2047;
    size_t fo = frag_off(m, k0);                 // k0%4==0 -> 4 consecutive ushorts, 8B aligned
    *(ushort4*)(dh + fo) = make_ushort4(h[0], h[1], h[2], h[3]);
    *(ushort4*)(dl + fo) = make_ushort4(l[0], l[1], l[2], l[3]);
}

// ---------------------------------------------------------------------------
// Transpose+split feat1 [2048][576] f32 -> Xh/Xl fragment-tile layout, rows 0..575.
__global__ __launch_bounds__(256) void split_xt_k(const float* __restrict__ feat1,
                                                  ushort* __restrict__ Xh, ushort* __restrict__ Xl) {
    __shared__ float tile[64][65];
    int n0 = blockIdx.x * 64, c0 = blockIdx.y * 64, tid = threadIdx.x;
#pragma unroll
    for (int i = 0; i < 16; ++i) {
        int idx = tid + i * 256;
        int cc = idx >> 6, nn = idx & 63;
        tile[cc][nn] = feat1[(size_t)(c0 + cc) * PIX + n0 + nn];
    }
    __syncthreads();
#pragma unroll
    for (int i = 0; i < 16; ++i) {
        int idx = tid + i * 256;
        int nn = idx >> 6, cc = idx & 63;
        float x = tile[cc][nn];
        unsigned hh = bf16rn(x);
        size_t fo = frag_off(n0 + nn, c0 + cc);
        Xh[fo] = (ushort)hh;
        Xl[fo] = (ushort)bf16rn(x - bf16tof(hh));
    }
}

// ---------------------------------------------------------------------------
// Rows 576..639 of Xh/Xl: pos tokens (split) for r<50, zeros for pad rows.
__global__ void split_pos_k(const float* __restrict__ pos,
                            ushort* __restrict__ Xh, ushort* __restrict__ Xl) {
    int g = blockIdx.x * 256 + threadIdx.x;     // 32768 threads, 4 elems each
    int r = g >> 9;                              // 0..63
    int c = (g & 511) * 4;
    float4 v = make_float4(0.f, 0.f, 0.f, 0.f);
    if (r < 50) v = *(const float4*)(pos + (size_t)r * CDIM + c);
    float xs[4] = {v.x, v.y, v.z, v.w};
    ushort h[4], l[4];
#pragma unroll
    for (int i = 0; i < 4; ++i) {
        unsigned hh = bf16rn(xs[i]);
        h[i] = (ushort)hh;
        l[i] = (ushort)bf16rn(xs[i] - bf16tof(hh));
    }
    size_t fo = frag_off(576 + r, c);
    *(ushort4*)(Xh + fo) = make_ushort4(h[0], h[1], h[2], h[3]);
    *(ushort4*)(Xl + fo) = make_ushort4(l[0], l[1], l[2], l[3]);
}

// ---------------------------------------------------------------------------
// Split-bf16 MFMA GEMM, 3-buffer depth-2 pipeline, coalesced frag-tile staging:
//   out[n][m] = sum_k W[m][k]*X[n][k]
// 3 products: WhXh + WhXl + WlXh. Tile 128m x 64n, BK=32, 4 waves (2x2, wave=64x32).
// Each slot load = one contiguous 1KB burst (lane*16B) -> single VMEM segment.
#define BUFB 24576
__global__ __launch_bounds__(256, 2) void gemm_bf16_k(
    const ushort* __restrict__ WhK, const ushort* __restrict__ WlK,
    const ushort* __restrict__ WhV, const ushort* __restrict__ WlV,
    const ushort* __restrict__ WhQ, const ushort* __restrict__ WlQ,
    const ushort* __restrict__ Xh, const ushort* __restrict__ Xl,
    const float* __restrict__ k_b, const float* __restrict__ v_b, const float* __restrict__ q_b,
    float* __restrict__ Kbuf, float* __restrict__ Vbuf, float* __restrict__ Qfull)
{
    __shared__ char smem[3 * BUFB];   // 72 KB: 3 rotating tile buffers
    int z = blockIdx.z;
    const ushort* Wh = z == 0 ? WhK : z == 1 ? WhV : WhQ;
    const ushort* Wl = z == 0 ? WlK : z == 1 ? WlV : WlQ;
    const float* bias = z == 0 ? k_b : z == 1 ? v_b : q_b;
    float* out = z == 0 ? Kbuf : z == 1 ? Vbuf : Qfull;
    int m0 = blockIdx.x * 128, n0 = blockIdx.y * 64;

    int tid = threadIdx.x, wid = tid >> 6, lane = tid & 63;
    int wm = wid >> 1, wn = wid & 1;

    // per-wave staging: 24 slot-loads/block, 6 per wave; each slot is a 16-row
    // fragment block whose k-tile t lives at base + t*1024 (contiguous 1KB).
    const char* gsrc[6];
    int ldsoff[6];
#pragma unroll
    for (int i = 0; i < 6; ++i) {
        int g = wid * 6 + i;
        const ushort* src; int r16; int off;
        if (g < 8)       { src = Wh; r16 = (m0 >> 4) + g;        off = g * 1024; }
        else if (g < 16) { src = Wl; r16 = (m0 >> 4) + (g - 8);  off = 8192 + (g - 8) * 1024; }
        else if (g < 20) { src = Xh; r16 = (n0 >> 4) + (g - 16); off = 16384 + (g - 16) * 1024; }
        else             { src = Xl; r16 = (n0 >> 4) + (g - 20); off = 20480 + (g - 20) * 1024; }
        gsrc[i] = (const char*)src + ((size_t)r16 * 64 * 1024) + lane * 16;
        ldsoff[i] = off;
    }

    f32x4 acc[4][2];
#pragma unroll
    for (int a = 0; a < 4; ++a)
#pragma unroll
        for (int b = 0; b < 2; ++b) acc[a][b] = (f32x4)0.f;

    // prologue: stage tiles 0 and 1 into buffers 0 and 1
#pragma unroll
    for (int i = 0; i < 6; ++i)
        __builtin_amdgcn_global_load_lds((as1c_void*)(gsrc[i]),
                                         (as3_void*)(smem + ldsoff[i]), 16, 0, 0);
#pragma unroll
    for (int i = 0; i < 6; ++i)
        __builtin_amdgcn_global_load_lds((as1c_void*)(gsrc[i] + 1024),
                                         (as3_void*)(smem + BUFB + ldsoff[i]), 16, 0, 0);
    asm volatile("s_waitcnt vmcnt(6)" ::: "memory");   // tile 0 complete
    __builtin_amdgcn_s_barrier();
    asm volatile("" ::: "memory");

    for (int t = 0; t < 64; ++t) {
        char* rbuf = smem + (t % 3) * BUFB;
        // stage tile t+2 into the buffer freed by tile t-1 (barrier'd)
        if (t < 62) {
            char* wbuf = smem + ((t + 2) % 3) * BUFB;
#pragma unroll
            for (int i = 0; i < 6; ++i)
                __builtin_amdgcn_global_load_lds((as1c_void*)(gsrc[i] + (size_t)(t + 2) * 1024),
                                                 (as3_void*)(wbuf + ldsoff[i]), 16, 0, 0);
        }

        short8 ah[4], al[4];
#pragma unroll
        for (int fm = 0; fm < 4; ++fm) {
            int s = wm * 4 + fm;
            ah[fm] = *(const short8*)(rbuf + s * 1024 + lane * 16);
            al[fm] = *(const short8*)(rbuf + 8192 + s * 1024 + lane * 16);
        }
        short8 bh[2], bl[2];
#pragma unroll
        for (int fn = 0; fn < 2; ++fn) {
            int s = wn * 2 + fn;
            bh[fn] = *(const short8*)(rbuf + 16384 + s * 1024 + lane * 16);
            bl[fn] = *(const short8*)(rbuf + 20480 + s * 1024 + lane * 16);
        }
#pragma unroll
        for (int fn = 0; fn < 2; ++fn)
#pragma unroll
            for (int fm = 0; fm < 4; ++fm) {
                acc[fm][fn] = __builtin_amdgcn_mfma_f32_16x16x32_bf16(ah[fm], bh[fn], acc[fm][fn], 0, 0, 0);
                acc[fm][fn] = __builtin_amdgcn_mfma_f32_16x16x32_bf16(ah[fm], bl[fn], acc[fm][fn], 0, 0, 0);
                acc[fm][fn] = __builtin_amdgcn_mfma_f32_16x16x32_bf16(al[fm], bh[fn], acc[fm][fn], 0, 0, 0);
            }

        // tile t+1 must be complete before next iter; keep t+2 in flight.
        if (t < 62) asm volatile("s_waitcnt vmcnt(6)" ::: "memory");
        else        asm volatile("s_waitcnt vmcnt(0)" ::: "memory");
        __builtin_amdgcn_s_barrier();
        asm volatile("" ::: "memory");
    }

    // epilogue: C/D layout col(n)=lane&15, row(m)=(lane>>4)*4+reg (m89-verified)
#pragma unroll
    for (int fm = 0; fm < 4; ++fm) {
        int mg = m0 + wm * 64 + fm * 16 + (lane >> 4) * 4;
        float4 bv = *(const float4*)(bias + mg);
#pragma unroll
        for (int fn = 0; fn < 2; ++fn) {
            int ng = n0 + wn * 32 + fn * 16 + (lane & 15);
            f32x4 o = acc[fm][fn];
            if (ng >= PIX) { o[0] += bv.x; o[1] += bv.y; o[2] += bv.z; o[3] += bv.w; }
            *(f32x4*)(out + (size_t)ng * CDIM + mg) = o;
        }
    }
}

// ---------------------------------------------------------------------------
// Qm[p][c] = mean over 7x7 window of Qfull pixel cols + Qfull[576] (pos0+bias)
// grid (NP, 2): c-halves; one float4/row/thread.
__global__ __launch_bounds__(256) void qmean_k(const float* __restrict__ Qfull, float* __restrict__ Qm) {
    int p = blockIdx.x;
    int i = p / WO, j = p % WO;
    int c = blockIdx.y * 1024 + threadIdx.x * 4;
    float4 s = make_float4(0.f, 0.f, 0.f, 0.f);
#pragma unroll 7
    for (int t = 0; t < 49; ++t) {
        int px = (i + t / 7) * WF + (j + t % 7);
        float4 v = *(const float4*)(Qfull + (size_t)px * CDIM + c);
        s.x += v.x; s.y += v.y; s.z += v.z; s.w += v.w;
    }
    float4 p0 = *(const float4*)(Qfull + (size_t)PIX * CDIM + c);
    float4 r;
    r.x = s.x * (1.f / 49.f) + p0.x;
    r.y = s.y * (1.f / 49.f) + p0.y;
    r.z = s.z * (1.f / 49.f) + p0.z;
    r.w = s.w * (1.f / 49.f) + p0.w;
    *(float4*)(Qm + (size_t)p * CDIM + c) = r;
}

// ---------------------------------------------------------------------------
// TW[j][c] = (txt_j/||txt_j||) . out_w[:,c];  cconst[j] = (txt_j/||..||) . out_b
__global__ __launch_bounds__(256) void txtw_k(
    const float* __restrict__ txt, const float* __restrict__ out_w, const float* __restrict__ out_b,
    float* __restrict__ TW, float* __restrict__ cconst)
{
    __shared__ float ts[OUTD];
    __shared__ float red[256], redb[256];
    int j = blockIdx.x, cb = blockIdx.y, tid = threadIdx.x;

    float n2 = 0.f, db = 0.f;
    for (int o = tid; o < OUTD; o += 256) {
        float tv = txt[(size_t)j * OUTD + o];
        ts[o] = tv;
        n2 += tv * tv;
        db += tv * out_b[o];
    }
    red[tid] = n2; redb[tid] = db;
    __syncthreads();
    for (int s = 128; s > 0; s >>= 1) {
        if (tid < s) { red[tid] += red[tid + s]; redb[tid] += redb[tid + s]; }
        __syncthreads();
    }
    float inv = 1.f / sqrtf(red[0]);

    int c = cb * 256 + tid;
    float acc = 0.f;
    for (int o = 0; o < OUTD; ++o)
        acc += ts[o] * out_w[(size_t)o * CDIM + c];
    TW[(size_t)j * CDIM + c] = acc * inv;
    if (cb == 0 && tid == 0) cconst[j] = redb[0] * inv;
}

// ---------------------------------------------------------------------------
// TV[col][h*NTXT+j] = sum_d TW[j][h*64+d] * V[col][h*64+d]
__global__ __launch_bounds__(256) void tv_k(
    const float* __restrict__ TW, const float* __restrict__ Vbuf, float* __restrict__ TV)
{
    __shared__ float TWs[NTXT * HD];
    __shared__ float Vs[8 * HD];
    int cg = blockIdx.x, h = blockIdx.y, tid = threadIdx.x;
    int c0 = cg * 8;

    for (int idx = tid; idx < NTXT * HD; idx += 256) {
        int j = idx / HD, d = idx % HD;
        TWs[idx] = TW[(size_t)j * CDIM + h * HD + d];
    }
    for (int idx = tid; idx < 8 * HD; idx += 256) {
        int c = idx / HD, d = idx % HD;
        int col = c0 + c;
        Vs[idx] = (col < NKV) ? Vbuf[(size_t)col * CDIM + h * HD + d] : 0.f;
    }
    __syncthreads();

    for (int o = tid; o < 8 * NTXT; o += 256) {
        int c = o / NTXT, j = o % NTXT;
        int col = c0 + c;
        if (col >= NKV) continue;
        float acc = 0.f;
#pragma unroll
        for (int d = 0; d < HD; d += 4) {
            float4 tw = *(const float4*)&TWs[j * HD + d];
            float4 vv = *(const float4*)&Vs[c * HD + d];
            acc += tw.x * vv.x + tw.y * vv.y + tw.z * vv.z + tw.w * vv.w;
        }
        TV[(size_t)col * HJ + h * NTXT + j] = acc;
    }
}

// ---------------------------------------------------------------------------
// Fused per-(patch, 8-head-slice) scores + softmax + folded pooling.
// grid (NP, 4), block 384 = 24 groups of 16 lanes.
// Score phase: each 16-lane group computes one (h,t) dot cooperatively --
// group reads one contiguous 256B K-segment (coalesced), shfl_xor reduce.
__global__ __launch_bounds__(384) void attn_fused_k(
    const float* __restrict__ Kbuf, const float* __restrict__ Qm,
    const float* __restrict__ TV, float* __restrict__ pooledHJ)
{
    __shared__ float qs[8 * HD];       // 512: q slice for 8 heads
    __shared__ float scf[8][NTOK];     // feature scores -> probs after softmax
    __shared__ float scp[8][NTOK];     // pos scores -> combined scores
    __shared__ int win[49];            // window pixel indices

    int p = blockIdx.x, s = blockIdx.y;
    int h0 = s * 8;
    int pi = p / WO, pj = p % WO;
    int tid = threadIdx.x;

    if (tid < 128)
        *(float4*)&qs[tid * 4] = *(const float4*)(Qm + (size_t)p * CDIM + h0 * HD + tid * 4);
    if (tid < 49)
        win[tid] = (pi + tid / 7) * WF + (pj + tid % 7);
    __syncthreads();

    // 792 dots: [0,392) feature (h = pair/49, t = pair%49 + 1, row = win[t-1]);
    //           [392,792) pos (h = (pair-392)/50, t = (pair-392)%50, row = PIX+t).
    // 24 groups x 33 iterations, no divergence.
    int grp = tid >> 4, gl = tid & 15;
#pragma unroll 3
    for (int i = 0; i < 33; ++i) {
        int pair = grp * 33 + i;
        int h, tt, row;
        if (pair < 392) { h = pair / 49; tt = pair % 49; row = win[tt]; }
        else { int q = pair - 392; h = q / 50; tt = q % 50; row = PIX + tt; }
        float4 kv = *(const float4*)(Kbuf + (size_t)row * CDIM + (h0 + h) * HD + gl * 4);
        float4 qv = *(const float4*)&qs[h * HD + gl * 4];
        float d = kv.x * qv.x + kv.y * qv.y + kv.z * qv.z + kv.w * qv.w;
        d += __shfl_xor(d, 1);
        d += __shfl_xor(d, 2);
        d += __shfl_xor(d, 4);
        d += __shfl_xor(d, 8);
        if (gl == 0) {
            if (pair < 392) scf[h][tt + 1] = d;
            else            scp[h][tt] = d;
        }
    }
    __syncthreads();

    // softmax per head; mean-token feature part = mean of scf[1..49]
    if (tid < 8) {
        int h = tid;
        float sF = 0.f;
        for (int t = 1; t < NTOK; ++t) sF += scf[h][t];
        scf[h][0] = sF * (1.f / 49.f);
        float m = -1e30f;
        for (int t = 0; t < NTOK; ++t) {
            float sc = (scf[h][t] + scp[h][t]) * 0.125f;
            scp[h][t] = sc;
            m = fmaxf(m, sc);
        }
        float ssum = 0.f;
        for (int t = 0; t < NTOK; ++t) { float e = expf(scp[h][t] - m); scf[h][t] = e; ssum += e; }
        float inv = 1.f / ssum;
        for (int t = 0; t < NTOK; ++t) scf[h][t] *= inv;
    }
    __syncthreads();

    // folded pooling for this slice's o-window (contiguous, coalesced)
    if (tid < 360) {
        int o = s * 360 + tid;
        int hloc = tid / 45;
        const float* apr = &scf[hloc][0];
        float lacc = 0.f, macc = 0.f;
#pragma unroll 7
        for (int t = 1; t < NTOK; ++t) {
            float a = apr[t];
            float v1 = TV[(size_t)win[t - 1] * HJ + o];
            float v2 = TV[(size_t)(PIX + t) * HJ + o];
            lacc += a * (v1 + v2);
            macc += v1;
        }
        float a0 = apr[0];
        lacc += a0 * (macc * (1.f / 49.f) + TV[(size_t)PIX * HJ + o]);
        pooledHJ[(size_t)p * HJ + o] = lacc;
    }
}

// ---------------------------------------------------------------------------
// finish: reduce pooledHJ over heads, add cconst, argmax -> bucket
__global__ __launch_bounds__(64) void finish_k(const float* __restrict__ pooledHJ,
                                               const float* __restrict__ cconst,
                                               int* __restrict__ bucket) {
    __shared__ float lg[NTXT];
    int p = blockIdx.x, lane = threadIdx.x;
    if (lane < NTXT) {
        float s = cconst[lane];
        const float* row = pooledHJ + (size_t)p * HJ;
#pragma unroll 8
        for (int h = 0; h < NHEAD; ++h) s += row[h * NTXT + lane];
        lg[lane] = s;
    }
    __syncthreads();
    if (lane == 0) {
        float best = lg[0]; int bi = 0;
        for (int j2 = 1; j2 < NTXT; ++j2)
            if (lg[j2] > best) { best = lg[j2]; bi = j2; }
        int bk = 0;
        const int bounds[5] = {8, 15, 22, 29, 36};
#pragma unroll
        for (int u = 0; u < 5; ++u) bk += (bi >= bounds[u]) ? 1 : 0;
        bucket[p] = bk;
    }
}

// ---------------------------------------------------------------------------
__global__ void votes_k(const int* __restrict__ bucket, float* __restrict__ maxval) {
    __shared__ int bk[NP];
    int tid = threadIdx.x;
    if (tid < NP) bk[tid] = bucket[tid];
    __syncthreads();
    if (tid < PIX) {
        int y = tid / WF, x = tid % WF;
        int cnt[6] = {0, 0, 0, 0, 0, 0};
        int i0 = (y - 6 < 0) ? 0 : y - 6;
        int i1 = (y > HO - 1) ? HO - 1 : y;
        int j0 = (x - 6 < 0) ? 0 : x - 6;
        int j1 = (x > WO - 1) ? WO - 1 : x;
        for (int i = i0; i <= i1; ++i)
            for (int j = j0; j <= j1; ++j)
                cnt[bk[i * WO + j]]++;
        int best = cnt[0], bi = 0;
#pragma unroll
        for (int ch = 1; ch < 6; ++ch)
            if (cnt[ch] > best) { best = cnt[ch]; bi = ch; }
        maxval[tid] = (bi > 0) ? 0.044194173824159216f : 0.f;
    }
}

__global__ void fill_k(const float* __restrict__ maxval, float* __restrict__ out) {
    int idx = blockIdx.x * 256 + threadIdx.x;
    const int HALF = OUTD * PIX;
    if (idx >= 2 * HALF) return;
    out[idx] = (idx < HALF) ? 0.f : maxval[idx % PIX];
}

// ---------------------------------------------------------------------------
extern "C" void kernel_launch(void* const* d_in, const int* in_sizes, int n_in,
                              void* d_out, int out_size, void* d_ws, size_t ws_size,
                              hipStream_t stream) {
    const float* imgf = (const float*)d_in[0];
    const float* txt  = (const float*)d_in[1];
    const float* pos  = (const float*)d_in[2];
    const float* q_w  = (const float*)d_in[3];
    const float* q_b  = (const float*)d_in[4];
    const float* k_w  = (const float*)d_in[5];
    const float* k_b  = (const float*)d_in[6];
    const float* v_w  = (const float*)d_in[7];
    const float* v_b  = (const float*)d_in[8];
    const float* o_w  = (const float*)d_in[9];
    const float* o_b  = (const float*)d_in[10];

    const float* feat1 = imgf + (size_t)1 * CDIM * PIX;   // only batch B-1=1 matters

    float* ws = (float*)d_ws;
    float* Kbuf  = ws;                                   // 640*2048
    float* Vbuf  = Kbuf + (size_t)NROWS * CDIM;
    float* Qfull = Vbuf + (size_t)NROWS * CDIM;
    float* Qm    = Qfull + (size_t)NROWS * CDIM;         // 324*2048
    float* TW    = Qm + (size_t)NP * CDIM;               // 45*2048
    float* cconst = TW + (size_t)NTXT * CDIM;            // 64
    float* TV    = cconst + 64;                          // 626*1440
    float* pooledHJ = TV + (size_t)NKV * HJ;             // 324*1440
    int*   bucket = (int*)(pooledHJ + (size_t)NP * HJ);  // 324
    float* maxval = (float*)(bucket + NP);               // 576
    size_t foff = (size_t)(maxval + 576 - ws);
    foff = (foff + 3) & ~(size_t)3;                      // 16B align
    ushort* WhK = (ushort*)(ws + foff);                  // each 2048*2048
    ushort* WlK = WhK + (size_t)CDIM * CDIM;
    ushort* WhV = WlK + (size_t)CDIM * CDIM;
    ushort* WlV = WhV + (size_t)CDIM * CDIM;
    ushort* WhQ = WlV + (size_t)CDIM * CDIM;
    ushort* WlQ = WhQ + (size_t)CDIM * CDIM;
    ushort* Xh  = WlQ + (size_t)CDIM * CDIM;             // 640*2048
    ushort* Xl  = Xh + (size_t)NROWS * CDIM;

    split_w_k<<<dim3(12288), dim3(256), 0, stream>>>(k_w, v_w, q_w, WhK, WlK, WhV, WlV, WhQ, WlQ);
    split_xt_k<<<dim3(9, 32), dim3(256), 0, stream>>>(feat1, Xh, Xl);
    split_pos_k<<<dim3(128), dim3(256), 0, stream>>>(pos, Xh, Xl);
    gemm_bf16_k<<<dim3(16, 10, 3), dim3(256), 0, stream>>>(WhK, WlK, WhV, WlV, WhQ, WlQ,
                                                           Xh, Xl, k_b, v_b, q_b, Kbuf, Vbuf, Qfull);
    qmean_k<<<dim3(NP, 2), dim3(256), 0, stream>>>(Qfull, Qm);
    txtw_k<<<dim3(NTXT, 8), dim3(256), 0, stream>>>(txt, o_w, o_b, TW, cconst);
    tv_k<<<dim3(79, 32), dim3(256), 0, stream>>>(TW, Vbuf, TV);
    attn_fused_k<<<dim3(NP, 4), dim3(384), 0, stream>>>(Kbuf, Qm, TV, pooledHJ);
    finish_k<<<dim3(NP), dim3(64), 0, stream>>>(pooledHJ, cconst, bucket);
    votes_k<<<dim3(1), dim3(576), 0, stream>>>(bucket, maxval);
    fill_k<<<dim3(2304), dim3(256), 0, stream>>>(maxval, (float*)d_out);
}

// Round 9
// 228.449 us; speedup vs baseline: 1.1572x; 1.0281x over previous
//
#include <hip/hip_runtime.h>
#include <math.h>

#define CDIM 2048
#define HF 24
#define WF 24
#define PIX 576
#define HO 18
#define WO 18
#define NP 324
#define NHEAD 32
#define HD 64
#define NTOK 50
#define NTXT 45
#define OUTD 512
#define NKV 626
#define HJ (NHEAD * NTXT)   // 1440
#define NROWS 640           // padded B rows: 576 pixels + 50 pos + 14 zero

typedef __attribute__((ext_vector_type(8))) short short8;
typedef __attribute__((ext_vector_type(4))) float f32x4;
typedef __attribute__((address_space(1))) const void as1c_void;
typedef __attribute__((address_space(3))) void as3_void;

__device__ inline unsigned bf16rn(float x) {
    unsigned u = __float_as_uint(x);
    return (u + 0x7FFFu + ((u >> 16) & 1u)) >> 16;
}
__device__ inline float bf16tof(unsigned h) { return __uint_as_float(h << 16); }

// Fragment-tile global layout (ushort element offset): tile (row>>4, k>>5) is
// 512 contiguous ushorts (1KB); global_load_lds reads it as lane*16B bursts.
__device__ inline size_t frag_off(int row, int k) {
    return (size_t)(((row >> 4) * 64 + (k >> 5)) * 512)
         + (size_t)(((k & 31) >> 3) * 128 + (row & 15) * 8 + (k & 7));
}

// ---------------------------------------------------------------------------
// Split the 3 weight matrices into hi/lo bf16, fragment-tile layout.
__global__ void split_w_k(const float* __restrict__ kw, const float* __restrict__ vw, const float* __restrict__ qw,
                          ushort* __restrict__ WhK, ushort* __restrict__ WlK,
                          ushort* __restrict__ WhV, ushort* __restrict__ WlV,
                          ushort* __restrict__ WhQ, ushort* __restrict__ WlQ) {
    int g = blockIdx.x * 256 + threadIdx.x;      // 3 * 1048576 threads, 4 elems each
    int sel = g >> 20;
    int off = (g & 1048575) * 4;                 // flat elem offset = m*2048 + k0, k0%4==0
    const float* src = sel == 0 ? kw : sel == 1 ? vw : qw;
    ushort* dh = sel == 0 ? WhK : sel == 1 ? WhV : WhQ;
    ushort* dl = sel == 0 ? WlK : sel == 1 ? WlV : WlQ;
    float4 v = *(const float4*)(src + off);
    float xs[4] = {v.x, v.y, v.z, v.w};
    ushort h[4], l[4];
#pragma unroll
    for (int i = 0; i < 4; ++i) {
        unsigned hh = bf16rn(xs[i]);
        h[i] = (ushort)hh;
        l[i] = (ushort)bf16rn(xs[i] - bf16tof(hh));
    }
    int m = off >> 11, k0 = off & 2047;
    size_t fo = frag_off(m, k0);
    *(ushort4*)(dh + fo) = make_ushort4(h[0], h[1], h[2], h[3]);
    *(ushort4*)(dl + fo) = make_ushort4(l[0], l[1], l[2], l[3]);
}

// ---------------------------------------------------------------------------
// Transpose+split feat1 [2048][576] f32 -> Xh/Xl fragment-tile layout, rows 0..575.
__global__ __launch_bounds__(256) void split_xt_k(const float* __restrict__ feat1,
                                                  ushort* __restrict__ Xh, ushort* __restrict__ Xl) {
    __shared__ float tile[64][65];
    int n0 = blockIdx.x * 64, c0 = blockIdx.y * 64, tid = threadIdx.x;
#pragma unroll
    for (int i = 0; i < 16; ++i) {
        int idx = tid + i * 256;
        int cc = idx >> 6, nn = idx & 63;
        tile[cc][nn] = feat1[(size_t)(c0 + cc) * PIX + n0 + nn];
    }
    __syncthreads();
#pragma unroll
    for (int i = 0; i < 16; ++i) {
        int idx = tid + i * 256;
        int nn = idx >> 6, cc = idx & 63;
        float x = tile[cc][nn];
        unsigned hh = bf16rn(x);
        size_t fo = frag_off(n0 + nn, c0 + cc);
        Xh[fo] = (ushort)hh;
        Xl[fo] = (ushort)bf16rn(x - bf16tof(hh));
    }
}

// ---------------------------------------------------------------------------
// Rows 576..639 of Xh/Xl: pos tokens (split) for r<50, zeros for pad rows.
__global__ void split_pos_k(const float* __restrict__ pos,
                            ushort* __restrict__ Xh, ushort* __restrict__ Xl) {
    int g = blockIdx.x * 256 + threadIdx.x;     // 32768 threads, 4 elems each
    int r = g >> 9;                              // 0..63
    int c = (g & 511) * 4;
    float4 v = make_float4(0.f, 0.f, 0.f, 0.f);
    if (r < 50) v = *(const float4*)(pos + (size_t)r * CDIM + c);
    float xs[4] = {v.x, v.y, v.z, v.w};
    ushort h[4], l[4];
#pragma unroll
    for (int i = 0; i < 4; ++i) {
        unsigned hh = bf16rn(xs[i]);
        h[i] = (ushort)hh;
        l[i] = (ushort)bf16rn(xs[i] - bf16tof(hh));
    }
    size_t fo = frag_off(576 + r, c);
    *(ushort4*)(Xh + fo) = make_ushort4(h[0], h[1], h[2], h[3]);
    *(ushort4*)(Xl + fo) = make_ushort4(l[0], l[1], l[2], l[3]);
}

// ---------------------------------------------------------------------------
// Split-bf16 MFMA GEMM, 3-buffer depth-2 pipeline, coalesced frag-tile staging.
#define BUFB 24576
__global__ __launch_bounds__(256, 2) void gemm_bf16_k(
    const ushort* __restrict__ WhK, const ushort* __restrict__ WlK,
    const ushort* __restrict__ WhV, const ushort* __restrict__ WlV,
    const ushort* __restrict__ WhQ, const ushort* __restrict__ WlQ,
    const ushort* __restrict__ Xh, const ushort* __restrict__ Xl,
    const float* __restrict__ k_b, const float* __restrict__ v_b, const float* __restrict__ q_b,
    float* __restrict__ Kbuf, float* __restrict__ Vbuf, float* __restrict__ Qfull)
{
    __shared__ char smem[3 * BUFB];   // 72 KB: 3 rotating tile buffers
    int z = blockIdx.z;
    const ushort* Wh = z == 0 ? WhK : z == 1 ? WhV : WhQ;
    const ushort* Wl = z == 0 ? WlK : z == 1 ? WlV : WlQ;
    const float* bias = z == 0 ? k_b : z == 1 ? v_b : q_b;
    float* out = z == 0 ? Kbuf : z == 1 ? Vbuf : Qfull;
    int m0 = blockIdx.x * 128, n0 = blockIdx.y * 64;

    int tid = threadIdx.x, wid = tid >> 6, lane = tid & 63;
    int wm = wid >> 1, wn = wid & 1;

    const char* gsrc[6];
    int ldsoff[6];
#pragma unroll
    for (int i = 0; i < 6; ++i) {
        int g = wid * 6 + i;
        const ushort* src; int r16; int off;
        if (g < 8)       { src = Wh; r16 = (m0 >> 4) + g;        off = g * 1024; }
        else if (g < 16) { src = Wl; r16 = (m0 >> 4) + (g - 8);  off = 8192 + (g - 8) * 1024; }
        else if (g < 20) { src = Xh; r16 = (n0 >> 4) + (g - 16); off = 16384 + (g - 16) * 1024; }
        else             { src = Xl; r16 = (n0 >> 4) + (g - 20); off = 20480 + (g - 20) * 1024; }
        gsrc[i] = (const char*)src + ((size_t)r16 * 64 * 1024) + lane * 16;
        ldsoff[i] = off;
    }

    f32x4 acc[4][2];
#pragma unroll
    for (int a = 0; a < 4; ++a)
#pragma unroll
        for (int b = 0; b < 2; ++b) acc[a][b] = (f32x4)0.f;

#pragma unroll
    for (int i = 0; i < 6; ++i)
        __builtin_amdgcn_global_load_lds((as1c_void*)(gsrc[i]),
                                         (as3_void*)(smem + ldsoff[i]), 16, 0, 0);
#pragma unroll
    for (int i = 0; i < 6; ++i)
        __builtin_amdgcn_global_load_lds((as1c_void*)(gsrc[i] + 1024),
                                         (as3_void*)(smem + BUFB + ldsoff[i]), 16, 0, 0);
    asm volatile("s_waitcnt vmcnt(6)" ::: "memory");   // tile 0 complete
    __builtin_amdgcn_s_barrier();
    asm volatile("" ::: "memory");

    for (int t = 0; t < 64; ++t) {
        char* rbuf = smem + (t % 3) * BUFB;
        if (t < 62) {
            char* wbuf = smem + ((t + 2) % 3) * BUFB;
#pragma unroll
            for (int i = 0; i < 6; ++i)
                __builtin_amdgcn_global_load_lds((as1c_void*)(gsrc[i] + (size_t)(t + 2) * 1024),
                                                 (as3_void*)(wbuf + ldsoff[i]), 16, 0, 0);
        }

        short8 ah[4], al[4];
#pragma unroll
        for (int fm = 0; fm < 4; ++fm) {
            int s = wm * 4 + fm;
            ah[fm] = *(const short8*)(rbuf + s * 1024 + lane * 16);
            al[fm] = *(const short8*)(rbuf + 8192 + s * 1024 + lane * 16);
        }
        short8 bh[2], bl[2];
#pragma unroll
        for (int fn = 0; fn < 2; ++fn) {
            int s = wn * 2 + fn;
            bh[fn] = *(const short8*)(rbuf + 16384 + s * 1024 + lane * 16);
            bl[fn] = *(const short8*)(rbuf + 20480 + s * 1024 + lane * 16);
        }
#pragma unroll
        for (int fn = 0; fn < 2; ++fn)
#pragma unroll
            for (int fm = 0; fm < 4; ++fm) {
                acc[fm][fn] = __builtin_amdgcn_mfma_f32_16x16x32_bf16(ah[fm], bh[fn], acc[fm][fn], 0, 0, 0);
                acc[fm][fn] = __builtin_amdgcn_mfma_f32_16x16x32_bf16(ah[fm], bl[fn], acc[fm][fn], 0, 0, 0);
                acc[fm][fn] = __builtin_amdgcn_mfma_f32_16x16x32_bf16(al[fm], bh[fn], acc[fm][fn], 0, 0, 0);
            }

        if (t < 62) asm volatile("s_waitcnt vmcnt(6)" ::: "memory");
        else        asm volatile("s_waitcnt vmcnt(0)" ::: "memory");
        __builtin_amdgcn_s_barrier();
        asm volatile("" ::: "memory");
    }

#pragma unroll
    for (int fm = 0; fm < 4; ++fm) {
        int mg = m0 + wm * 64 + fm * 16 + (lane >> 4) * 4;
        float4 bv = *(const float4*)(bias + mg);
#pragma unroll
        for (int fn = 0; fn < 2; ++fn) {
            int ng = n0 + wn * 32 + fn * 16 + (lane & 15);
            f32x4 o = acc[fm][fn];
            if (ng >= PIX) { o[0] += bv.x; o[1] += bv.y; o[2] += bv.z; o[3] += bv.w; }
            *(f32x4*)(out + (size_t)ng * CDIM + mg) = o;
        }
    }
}

// ---------------------------------------------------------------------------
// Qm[p][c] = mean over 7x7 window of Qfull pixel cols + Qfull[576] (pos0+bias)
__global__ __launch_bounds__(256) void qmean_k(const float* __restrict__ Qfull, float* __restrict__ Qm) {
    int p = blockIdx.x;
    int i = p / WO, j = p % WO;
    int c = blockIdx.y * 1024 + threadIdx.x * 4;
    float4 s = make_float4(0.f, 0.f, 0.f, 0.f);
#pragma unroll 7
    for (int t = 0; t < 49; ++t) {
        int px = (i + t / 7) * WF + (j + t % 7);
        float4 v = *(const float4*)(Qfull + (size_t)px * CDIM + c);
        s.x += v.x; s.y += v.y; s.z += v.z; s.w += v.w;
    }
    float4 p0 = *(const float4*)(Qfull + (size_t)PIX * CDIM + c);
    float4 r;
    r.x = s.x * (1.f / 49.f) + p0.x;
    r.y = s.y * (1.f / 49.f) + p0.y;
    r.z = s.z * (1.f / 49.f) + p0.z;
    r.w = s.w * (1.f / 49.f) + p0.w;
    *(float4*)(Qm + (size_t)p * CDIM + c) = r;
}

// ---------------------------------------------------------------------------
// POSS[p][h][t] = Qm[p][h-slice] . Kbuf[PIX+t][h-slice]   (pos scores, all patches)
// grid (81, 32), block 256: 4 patches x 50 tokens per block, one head.
__global__ __launch_bounds__(256) void poss_k(const float* __restrict__ Kbuf,
                                              const float* __restrict__ Qm,
                                              float* __restrict__ POSS) {
    __shared__ float qsl[4 * HD];
    int pb = blockIdx.x * 4, h = blockIdx.y, tid = threadIdx.x;
    qsl[tid] = Qm[(size_t)(pb + (tid >> 6)) * CDIM + h * HD + (tid & 63)];
    __syncthreads();
    if (tid < 200) {
        int pp = tid / 50, t = tid % 50;
        const float* kp = Kbuf + (size_t)(PIX + t) * CDIM + h * HD;
        const float* q = &qsl[pp * HD];
        float dot = 0.f;
#pragma unroll
        for (int d = 0; d < HD; d += 4) {
            float4 kv = *(const float4*)&kp[d];
            dot += kv.x * q[d] + kv.y * q[d + 1] + kv.z * q[d + 2] + kv.w * q[d + 3];
        }
        POSS[(size_t)(pb + pp) * (NHEAD * NTOK) + h * NTOK + t] = dot;
    }
}

// ---------------------------------------------------------------------------
// TW[j][c] = (txt_j/||txt_j||) . out_w[:,c];  cconst[j] = (txt_j/||..||) . out_b
__global__ __launch_bounds__(256) void txtw_k(
    const float* __restrict__ txt, const float* __restrict__ out_w, const float* __restrict__ out_b,
    float* __restrict__ TW, float* __restrict__ cconst)
{
    __shared__ float ts[OUTD];
    __shared__ float red[256], redb[256];
    int j = blockIdx.x, cb = blockIdx.y, tid = threadIdx.x;

    float n2 = 0.f, db = 0.f;
    for (int o = tid; o < OUTD; o += 256) {
        float tv = txt[(size_t)j * OUTD + o];
        ts[o] = tv;
        n2 += tv * tv;
        db += tv * out_b[o];
    }
    red[tid] = n2; redb[tid] = db;
    __syncthreads();
    for (int s = 128; s > 0; s >>= 1) {
        if (tid < s) { red[tid] += red[tid + s]; redb[tid] += redb[tid + s]; }
        __syncthreads();
    }
    float inv = 1.f / sqrtf(red[0]);

    int c = cb * 256 + tid;
    float acc = 0.f;
    for (int o = 0; o < OUTD; ++o)
        acc += ts[o] * out_w[(size_t)o * CDIM + c];
    TW[(size_t)j * CDIM + c] = acc * inv;
    if (cb == 0 && tid == 0) cconst[j] = redb[0] * inv;
}

// ---------------------------------------------------------------------------
// TV[col][h*NTXT+j] = sum_d TW[j][h*64+d] * V[col][h*64+d]
__global__ __launch_bounds__(256) void tv_k(
    const float* __restrict__ TW, const float* __restrict__ Vbuf, float* __restrict__ TV)
{
    __shared__ float TWs[NTXT * HD];
    __shared__ float Vs[8 * HD];
    int cg = blockIdx.x, h = blockIdx.y, tid = threadIdx.x;
    int c0 = cg * 8;

    for (int idx = tid; idx < NTXT * HD; idx += 256) {
        int j = idx / HD, d = idx % HD;
        TWs[idx] = TW[(size_t)j * CDIM + h * HD + d];
    }
    for (int idx = tid; idx < 8 * HD; idx += 256) {
        int c = idx / HD, d = idx % HD;
        int col = c0 + c;
        Vs[idx] = (col < NKV) ? Vbuf[(size_t)col * CDIM + h * HD + d] : 0.f;
    }
    __syncthreads();

    for (int o = tid; o < 8 * NTXT; o += 256) {
        int c = o / NTXT, j = o % NTXT;
        int col = c0 + c;
        if (col >= NKV) continue;
        float acc = 0.f;
#pragma unroll
        for (int d = 0; d < HD; d += 4) {
            float4 tw = *(const float4*)&TWs[j * HD + d];
            float4 vv = *(const float4*)&Vs[c * HD + d];
            acc += tw.x * vv.x + tw.y * vv.y + tw.z * vv.z + tw.w * vv.w;
        }
        TV[(size_t)col * HJ + h * NTXT + j] = acc;
    }
}

// ---------------------------------------------------------------------------
// Fused per-(patch, 8-head-slice) scores + softmax + folded pooling, v3:
//  - grid 1296 linear, XCD-swizzled so each XCD owns one head-slice s
//    (slice working set ~2.5MB < 4MB per-XCD L2): s = (id&7)>>1, p = (id>>3)*2 + (id&1)
//  - pos scores from precomputed POSS (no Kpos dots in-kernel)
//  - 16-lane-group parallel softmax (12 shfl vs serial 50-iter loops)
__global__ __launch_bounds__(384) void attn_fused_k(
    const float* __restrict__ Kbuf, const float* __restrict__ Qm,
    const float* __restrict__ TV, const float* __restrict__ POSS,
    float* __restrict__ pooledHJ)
{
    __shared__ float qs[8 * HD];       // q slice for 8 heads
    __shared__ float scf[8][NTOK];     // feature scores -> probs after softmax
    __shared__ float scp[8][NTOK];     // pos scores (from POSS)
    __shared__ int win[49];

    int flat = blockIdx.x;
    int s = (flat & 7) >> 1;
    int p = (flat >> 3) * 2 + (flat & 1);
    int h0 = s * 8;
    int pi = p / WO, pj = p % WO;
    int tid = threadIdx.x;

    if (tid < 128)
        *(float4*)&qs[tid * 4] = *(const float4*)(Qm + (size_t)p * CDIM + h0 * HD + tid * 4);
    if (tid < 49)
        win[tid] = (pi + tid / 7) * WF + (pj + tid % 7);
    for (int u = tid; u < 8 * NTOK; u += 384)
        scp[u / NTOK][u % NTOK] = POSS[(size_t)p * (NHEAD * NTOK) + h0 * NTOK + u];
    __syncthreads();

    // 392 feature dots (h, t=tt+1, row=win[tt]); 24 groups x 17 iters, stride-24.
    int grp = tid >> 4, gl = tid & 15;
    for (int i = 0; i < 17; ++i) {
        int pair = i * 24 + grp;
        if (pair < 392) {
            int h = pair / 49, tt = pair % 49;
            float4 kv = *(const float4*)(Kbuf + (size_t)win[tt] * CDIM + (h0 + h) * HD + gl * 4);
            float4 qv = *(const float4*)&qs[h * HD + gl * 4];
            float d = kv.x * qv.x + kv.y * qv.y + kv.z * qv.z + kv.w * qv.w;
            d += __shfl_xor(d, 1);
            d += __shfl_xor(d, 2);
            d += __shfl_xor(d, 4);
            d += __shfl_xor(d, 8);
            if (gl == 0) scf[h][tt + 1] = d;
        }
    }
    __syncthreads();

    // parallel softmax: group grp<8 = head, lanes cover tokens {gl, gl+16, gl+32, gl+48}
    if (tid < 128) {
        int h = grp;
        float sloc = 0.f;
#pragma unroll
        for (int i = 0; i < 4; ++i) {
            int t = gl + 16 * i;
            if (t >= 1 && t < NTOK) sloc += scf[h][t];
        }
        sloc += __shfl_xor(sloc, 1); sloc += __shfl_xor(sloc, 2);
        sloc += __shfl_xor(sloc, 4); sloc += __shfl_xor(sloc, 8);
        float s0 = sloc * (1.f / 49.f);

        float sc[4];
        float mloc = -1e30f;
#pragma unroll
        for (int i = 0; i < 4; ++i) {
            int t = gl + 16 * i;
            if (t < NTOK) {
                float base = (t == 0) ? s0 : scf[h][t];
                sc[i] = (base + scp[h][t]) * 0.125f;
                mloc = fmaxf(mloc, sc[i]);
            }
        }
        mloc = fmaxf(mloc, __shfl_xor(mloc, 1)); mloc = fmaxf(mloc, __shfl_xor(mloc, 2));
        mloc = fmaxf(mloc, __shfl_xor(mloc, 4)); mloc = fmaxf(mloc, __shfl_xor(mloc, 8));

        float ev[4];
        float eloc = 0.f;
#pragma unroll
        for (int i = 0; i < 4; ++i) {
            int t = gl + 16 * i;
            if (t < NTOK) { ev[i] = expf(sc[i] - mloc); eloc += ev[i]; }
        }
        eloc += __shfl_xor(eloc, 1); eloc += __shfl_xor(eloc, 2);
        eloc += __shfl_xor(eloc, 4); eloc += __shfl_xor(eloc, 8);
        float inv = 1.f / eloc;
#pragma unroll
        for (int i = 0; i < 4; ++i) {
            int t = gl + 16 * i;
            if (t < NTOK) scf[h][t] = ev[i] * inv;
        }
    }
    __syncthreads();

    // folded pooling for this slice's o-window (contiguous, coalesced)
    if (tid < 360) {
        int o = s * 360 + tid;
        int hloc = tid / 45;
        const float* apr = &scf[hloc][0];
        float lacc = 0.f, macc = 0.f;
#pragma unroll 7
        for (int t = 1; t < NTOK; ++t) {
            float a = apr[t];
            float v1 = TV[(size_t)win[t - 1] * HJ + o];
            float v2 = TV[(size_t)(PIX + t) * HJ + o];
            lacc += a * (v1 + v2);
            macc += v1;
        }
        float a0 = apr[0];
        lacc += a0 * (macc * (1.f / 49.f) + TV[(size_t)PIX * HJ + o]);
        pooledHJ[(size_t)p * HJ + o] = lacc;
    }
}

// ---------------------------------------------------------------------------
// finish: reduce pooledHJ over heads, add cconst, argmax -> bucket
__global__ __launch_bounds__(64) void finish_k(const float* __restrict__ pooledHJ,
                                               const float* __restrict__ cconst,
                                               int* __restrict__ bucket) {
    __shared__ float lg[NTXT];
    int p = blockIdx.x, lane = threadIdx.x;
    if (lane < NTXT) {
        float s = cconst[lane];
        const float* row = pooledHJ + (size_t)p * HJ;
#pragma unroll 8
        for (int h = 0; h < NHEAD; ++h) s += row[h * NTXT + lane];
        lg[lane] = s;
    }
    __syncthreads();
    if (lane == 0) {
        float best = lg[0]; int bi = 0;
        for (int j2 = 1; j2 < NTXT; ++j2)
            if (lg[j2] > best) { best = lg[j2]; bi = j2; }
        int bk = 0;
        const int bounds[5] = {8, 15, 22, 29, 36};
#pragma unroll
        for (int u = 0; u < 5; ++u) bk += (bi >= bounds[u]) ? 1 : 0;
        bucket[p] = bk;
    }
}

// ---------------------------------------------------------------------------
__global__ void votes_k(const int* __restrict__ bucket, float* __restrict__ maxval) {
    __shared__ int bk[NP];
    int tid = threadIdx.x;
    if (tid < NP) bk[tid] = bucket[tid];
    __syncthreads();
    if (tid < PIX) {
        int y = tid / WF, x = tid % WF;
        int cnt[6] = {0, 0, 0, 0, 0, 0};
        int i0 = (y - 6 < 0) ? 0 : y - 6;
        int i1 = (y > HO - 1) ? HO - 1 : y;
        int j0 = (x - 6 < 0) ? 0 : x - 6;
        int j1 = (x > WO - 1) ? WO - 1 : x;
        for (int i = i0; i <= i1; ++i)
            for (int j = j0; j <= j1; ++j)
                cnt[bk[i * WO + j]]++;
        int best = cnt[0], bi = 0;
#pragma unroll
        for (int ch = 1; ch < 6; ++ch)
            if (cnt[ch] > best) { best = cnt[ch]; bi = ch; }
        maxval[tid] = (bi > 0) ? 0.044194173824159216f : 0.f;
    }
}

__global__ void fill_k(const float* __restrict__ maxval, float* __restrict__ out) {
    int idx = blockIdx.x * 256 + threadIdx.x;
    const int HALF = OUTD * PIX;
    if (idx >= 2 * HALF) return;
    out[idx] = (idx < HALF) ? 0.f : maxval[idx % PIX];
}

// ---------------------------------------------------------------------------
extern "C" void kernel_launch(void* const* d_in, const int* in_sizes, int n_in,
                              void* d_out, int out_size, void* d_ws, size_t ws_size,
                              hipStream_t stream) {
    const float* imgf = (const float*)d_in[0];
    const float* txt  = (const float*)d_in[1];
    const float* pos  = (const float*)d_in[2];
    const float* q_w  = (const float*)d_in[3];
    const float* q_b  = (const float*)d_in[4];
    const float* k_w  = (const float*)d_in[5];
    const float* k_b  = (const float*)d_in[6];
    const float* v_w  = (const float*)d_in[7];
    const float* v_b  = (const float*)d_in[8];
    const float* o_w  = (const float*)d_in[9];
    const float* o_b  = (const float*)d_in[10];

    const float* feat1 = imgf + (size_t)1 * CDIM * PIX;   // only batch B-1=1 matters

    float* ws = (float*)d_ws;
    float* Kbuf  = ws;                                   // 640*2048
    float* Vbuf  = Kbuf + (size_t)NROWS * CDIM;
    float* Qfull = Vbuf + (size_t)NROWS * CDIM;
    float* Qm    = Qfull + (size_t)NROWS * CDIM;         // 324*2048
    float* TW    = Qm + (size_t)NP * CDIM;               // 45*2048
    float* cconst = TW + (size_t)NTXT * CDIM;            // 64
    float* TV    = cconst + 64;                          // 626*1440
    float* pooledHJ = TV + (size_t)NKV * HJ;             // 324*1440
    float* POSS  = pooledHJ + (size_t)NP * HJ;           // 324*1600
    int*   bucket = (int*)(POSS + (size_t)NP * NHEAD * NTOK);  // 324
    float* maxval = (float*)(bucket + NP);               // 576
    size_t foff = (size_t)(maxval + 576 - ws);
    foff = (foff + 3) & ~(size_t)3;                      // 16B align
    ushort* WhK = (ushort*)(ws + foff);                  // each 2048*2048
    ushort* WlK = WhK + (size_t)CDIM * CDIM;
    ushort* WhV = WlK + (size_t)CDIM * CDIM;
    ushort* WlV = WhV + (size_t)CDIM * CDIM;
    ushort* WhQ = WlV + (size_t)CDIM * CDIM;
    ushort* WlQ = WhQ + (size_t)CDIM * CDIM;
    ushort* Xh  = WlQ + (size_t)CDIM * CDIM;             // 640*2048
    ushort* Xl  = Xh + (size_t)NROWS * CDIM;

    split_w_k<<<dim3(12288), dim3(256), 0, stream>>>(k_w, v_w, q_w, WhK, WlK, WhV, WlV, WhQ, WlQ);
    split_xt_k<<<dim3(9, 32), dim3(256), 0, stream>>>(feat1, Xh, Xl);
    split_pos_k<<<dim3(128), dim3(256), 0, stream>>>(pos, Xh, Xl);
    gemm_bf16_k<<<dim3(16, 10, 3), dim3(256), 0, stream>>>(WhK, WlK, WhV, WlV, WhQ, WlQ,
                                                           Xh, Xl, k_b, v_b, q_b, Kbuf, Vbuf, Qfull);
    qmean_k<<<dim3(NP, 2), dim3(256), 0, stream>>>(Qfull, Qm);
    poss_k<<<dim3(81, 32), dim3(256), 0, stream>>>(Kbuf, Qm, POSS);
    txtw_k<<<dim3(NTXT, 8), dim3(256), 0, stream>>>(txt, o_w, o_b, TW, cconst);
    tv_k<<<dim3(79, 32), dim3(256), 0, stream>>>(TW, Vbuf, TV);
    attn_fused_k<<<dim3(NP * 4), dim3(384), 0, stream>>>(Kbuf, Qm, TV, POSS, pooledHJ);
    finish_k<<<dim3(NP), dim3(64), 0, stream>>>(pooledHJ, cconst, bucket);
    votes_k<<<dim3(1), dim3(576), 0, stream>>>(bucket, maxval);
    fill_k<<<dim3(2304), dim3(256), 0, stream>>>(maxval, (float*)d_out);
}

// Round 10
// 199.129 us; speedup vs baseline: 1.3276x; 1.1472x over previous
//
#include <hip/hip_runtime.h>
#include <math.h>

#define CDIM 2048
#define HF 24
#define WF 24
#define PIX 576
#define HO 18
#define WO 18
#define NP 324
#define NHEAD 32
#define HD 64
#define NTOK 50
#define NTXT 45
#define OUTD 512
#define NKV 626
#define HJ (NHEAD * NTXT)   // 1440
#define NROWS 640           // padded B rows: 576 pixels + 50 pos + 14 zero

typedef __attribute__((ext_vector_type(8))) short short8;
typedef __attribute__((ext_vector_type(4))) float f32x4;
typedef __attribute__((address_space(1))) const void as1c_void;
typedef __attribute__((address_space(3))) void as3_void;

__device__ inline unsigned bf16rn(float x) {
    unsigned u = __float_as_uint(x);
    return (u + 0x7FFFu + ((u >> 16) & 1u)) >> 16;
}
__device__ inline float bf16tof(unsigned h) { return __uint_as_float(h << 16); }

// Fragment-tile global layout (ushort element offset): tile (row>>4, k>>5) is
// 512 contiguous ushorts (1KB); global_load_lds reads it as lane*16B bursts.
__device__ inline size_t frag_off(int row, int k) {
    return (size_t)(((row >> 4) * 64 + (k >> 5)) * 512)
         + (size_t)(((k & 31) >> 3) * 128 + (row & 15) * 8 + (k & 7));
}

// ---------------------------------------------------------------------------
// Split the 3 weight matrices into hi/lo bf16, fragment-tile layout.
// One wave per 16x32 tile: lane (chunk*16+lrow) reads 8 consecutive floats of
// row (m16*16+lrow), writes its 16B slot at tile_base + lane*16 -- the 1KB
// tile is written contiguously by the wave (no partial-line RMW).
__global__ __launch_bounds__(256) void split_w_k(
    const float* __restrict__ kw, const float* __restrict__ vw, const float* __restrict__ qw,
    ushort* __restrict__ WhK, ushort* __restrict__ WlK,
    ushort* __restrict__ WhV, ushort* __restrict__ WlV,
    ushort* __restrict__ WhQ, ushort* __restrict__ WlQ) {
    int gw = blockIdx.x * 4 + (threadIdx.x >> 6);   // global tile id, 3*8192 total
    int lane = threadIdx.x & 63;
    int sel = gw >> 13;                             // matrix (8192 tiles each)
    int tl = gw & 8191;
    int m16 = tl >> 6;                              // row-tile (m/16)
    int kt = tl & 63;                               // k-tile (k/32)
    const float* src = sel == 0 ? kw : sel == 1 ? vw : qw;
    ushort* dh = sel == 0 ? WhK : sel == 1 ? WhV : WhQ;
    ushort* dl = sel == 0 ? WlK : sel == 1 ? WlV : WlQ;

    int row = m16 * 16 + (lane & 15);
    int k = kt * 32 + (lane >> 4) * 8;
    const float* sp = src + (size_t)row * CDIM + k;
    float4 a = *(const float4*)sp;
    float4 b = *(const float4*)(sp + 4);
    float xs[8] = {a.x, a.y, a.z, a.w, b.x, b.y, b.z, b.w};
    short8 hv, lv;
#pragma unroll
    for (int i = 0; i < 8; ++i) {
        unsigned hh = bf16rn(xs[i]);
        hv[i] = (short)hh;
        lv[i] = (short)bf16rn(xs[i] - bf16tof(hh));
    }
    size_t to = (size_t)tl * 512 + lane * 8;
    *(short8*)(dh + to) = hv;
    *(short8*)(dl + to) = lv;
}

// ---------------------------------------------------------------------------
// Transpose+split feat1 [2048][576] f32 -> Xh/Xl fragment-tile layout, rows 0..575.
__global__ __launch_bounds__(256) void split_xt_k(const float* __restrict__ feat1,
                                                  ushort* __restrict__ Xh, ushort* __restrict__ Xl) {
    __shared__ float tile[64][65];
    int n0 = blockIdx.x * 64, c0 = blockIdx.y * 64, tid = threadIdx.x;
#pragma unroll
    for (int i = 0; i < 16; ++i) {
        int idx = tid + i * 256;
        int cc = idx >> 6, nn = idx & 63;
        tile[cc][nn] = feat1[(size_t)(c0 + cc) * PIX + n0 + nn];
    }
    __syncthreads();
#pragma unroll
    for (int i = 0; i < 16; ++i) {
        int idx = tid + i * 256;
        int nn = idx >> 6, cc = idx & 63;
        float x = tile[cc][nn];
        unsigned hh = bf16rn(x);
        size_t fo = frag_off(n0 + nn, c0 + cc);
        Xh[fo] = (ushort)hh;
        Xl[fo] = (ushort)bf16rn(x - bf16tof(hh));
    }
}

// ---------------------------------------------------------------------------
// Rows 576..639 of Xh/Xl: pos tokens (split) for r<50, zeros for pad rows.
__global__ void split_pos_k(const float* __restrict__ pos,
                            ushort* __restrict__ Xh, ushort* __restrict__ Xl) {
    int g = blockIdx.x * 256 + threadIdx.x;     // 32768 threads, 4 elems each
    int r = g >> 9;                              // 0..63
    int c = (g & 511) * 4;
    float4 v = make_float4(0.f, 0.f, 0.f, 0.f);
    if (r < 50) v = *(const float4*)(pos + (size_t)r * CDIM + c);
    float xs[4] = {v.x, v.y, v.z, v.w};
    ushort h[4], l[4];
#pragma unroll
    for (int i = 0; i < 4; ++i) {
        unsigned hh = bf16rn(xs[i]);
        h[i] = (ushort)hh;
        l[i] = (ushort)bf16rn(xs[i] - bf16tof(hh));
    }
    size_t fo = frag_off(576 + r, c);
    *(ushort4*)(Xh + fo) = make_ushort4(h[0], h[1], h[2], h[3]);
    *(ushort4*)(Xl + fo) = make_ushort4(l[0], l[1], l[2], l[3]);
}

// ---------------------------------------------------------------------------
// Split-bf16 MFMA GEMM, 3-buffer depth-2 pipeline, coalesced frag-tile staging.
#define BUFB 24576
__global__ __launch_bounds__(256, 2) void gemm_bf16_k(
    const ushort* __restrict__ WhK, const ushort* __restrict__ WlK,
    const ushort* __restrict__ WhV, const ushort* __restrict__ WlV,
    const ushort* __restrict__ WhQ, const ushort* __restrict__ WlQ,
    const ushort* __restrict__ Xh, const ushort* __restrict__ Xl,
    const float* __restrict__ k_b, const float* __restrict__ v_b, const float* __restrict__ q_b,
    float* __restrict__ Kbuf, float* __restrict__ Vbuf, float* __restrict__ Qfull)
{
    __shared__ char smem[3 * BUFB];   // 72 KB: 3 rotating tile buffers
    int z = blockIdx.z;
    const ushort* Wh = z == 0 ? WhK : z == 1 ? WhV : WhQ;
    const ushort* Wl = z == 0 ? WlK : z == 1 ? WlV : WlQ;
    const float* bias = z == 0 ? k_b : z == 1 ? v_b : q_b;
    float* out = z == 0 ? Kbuf : z == 1 ? Vbuf : Qfull;
    int m0 = blockIdx.x * 128, n0 = blockIdx.y * 64;

    int tid = threadIdx.x, wid = tid >> 6, lane = tid & 63;
    int wm = wid >> 1, wn = wid & 1;

    const char* gsrc[6];
    int ldsoff[6];
#pragma unroll
    for (int i = 0; i < 6; ++i) {
        int g = wid * 6 + i;
        const ushort* src; int r16; int off;
        if (g < 8)       { src = Wh; r16 = (m0 >> 4) + g;        off = g * 1024; }
        else if (g < 16) { src = Wl; r16 = (m0 >> 4) + (g - 8);  off = 8192 + (g - 8) * 1024; }
        else if (g < 20) { src = Xh; r16 = (n0 >> 4) + (g - 16); off = 16384 + (g - 16) * 1024; }
        else             { src = Xl; r16 = (n0 >> 4) + (g - 20); off = 20480 + (g - 20) * 1024; }
        gsrc[i] = (const char*)src + ((size_t)r16 * 64 * 1024) + lane * 16;
        ldsoff[i] = off;
    }

    f32x4 acc[4][2];
#pragma unroll
    for (int a = 0; a < 4; ++a)
#pragma unroll
        for (int b = 0; b < 2; ++b) acc[a][b] = (f32x4)0.f;

#pragma unroll
    for (int i = 0; i < 6; ++i)
        __builtin_amdgcn_global_load_lds((as1c_void*)(gsrc[i]),
                                         (as3_void*)(smem + ldsoff[i]), 16, 0, 0);
#pragma unroll
    for (int i = 0; i < 6; ++i)
        __builtin_amdgcn_global_load_lds((as1c_void*)(gsrc[i] + 1024),
                                         (as3_void*)(smem + BUFB + ldsoff[i]), 16, 0, 0);
    asm volatile("s_waitcnt vmcnt(6)" ::: "memory");   // tile 0 complete
    __builtin_amdgcn_s_barrier();
    asm volatile("" ::: "memory");

    for (int t = 0; t < 64; ++t) {
        char* rbuf = smem + (t % 3) * BUFB;
        if (t < 62) {
            char* wbuf = smem + ((t + 2) % 3) * BUFB;
#pragma unroll
            for (int i = 0; i < 6; ++i)
                __builtin_amdgcn_global_load_lds((as1c_void*)(gsrc[i] + (size_t)(t + 2) * 1024),
                                                 (as3_void*)(wbuf + ldsoff[i]), 16, 0, 0);
        }

        short8 ah[4], al[4];
#pragma unroll
        for (int fm = 0; fm < 4; ++fm) {
            int s = wm * 4 + fm;
            ah[fm] = *(const short8*)(rbuf + s * 1024 + lane * 16);
            al[fm] = *(const short8*)(rbuf + 8192 + s * 1024 + lane * 16);
        }
        short8 bh[2], bl[2];
#pragma unroll
        for (int fn = 0; fn < 2; ++fn) {
            int s = wn * 2 + fn;
            bh[fn] = *(const short8*)(rbuf + 16384 + s * 1024 + lane * 16);
            bl[fn] = *(const short8*)(rbuf + 20480 + s * 1024 + lane * 16);
        }
#pragma unroll
        for (int fn = 0; fn < 2; ++fn)
#pragma unroll
            for (int fm = 0; fm < 4; ++fm) {
                acc[fm][fn] = __builtin_amdgcn_mfma_f32_16x16x32_bf16(ah[fm], bh[fn], acc[fm][fn], 0, 0, 0);
                acc[fm][fn] = __builtin_amdgcn_mfma_f32_16x16x32_bf16(ah[fm], bl[fn], acc[fm][fn], 0, 0, 0);
                acc[fm][fn] = __builtin_amdgcn_mfma_f32_16x16x32_bf16(al[fm], bh[fn], acc[fm][fn], 0, 0, 0);
            }

        if (t < 62) asm volatile("s_waitcnt vmcnt(6)" ::: "memory");
        else        asm volatile("s_waitcnt vmcnt(0)" ::: "memory");
        __builtin_amdgcn_s_barrier();
        asm volatile("" ::: "memory");
    }

#pragma unroll
    for (int fm = 0; fm < 4; ++fm) {
        int mg = m0 + wm * 64 + fm * 16 + (lane >> 4) * 4;
        float4 bv = *(const float4*)(bias + mg);
#pragma unroll
        for (int fn = 0; fn < 2; ++fn) {
            int ng = n0 + wn * 32 + fn * 16 + (lane & 15);
            f32x4 o = acc[fm][fn];
            if (ng >= PIX) { o[0] += bv.x; o[1] += bv.y; o[2] += bv.z; o[3] += bv.w; }
            *(f32x4*)(out + (size_t)ng * CDIM + mg) = o;
        }
    }
}

// ---------------------------------------------------------------------------
// Qm[p][c] = mean over 7x7 window of Qfull pixel cols + Qfull[576] (pos0+bias)
__global__ __launch_bounds__(256) void qmean_k(const float* __restrict__ Qfull, float* __restrict__ Qm) {
    int p = blockIdx.x;
    int i = p / WO, j = p % WO;
    int c = blockIdx.y * 1024 + threadIdx.x * 4;
    float4 s = make_float4(0.f, 0.f, 0.f, 0.f);
#pragma unroll 7
    for (int t = 0; t < 49; ++t) {
        int px = (i + t / 7) * WF + (j + t % 7);
        float4 v = *(const float4*)(Qfull + (size_t)px * CDIM + c);
        s.x += v.x; s.y += v.y; s.z += v.z; s.w += v.w;
    }
    float4 p0 = *(const float4*)(Qfull + (size_t)PIX * CDIM + c);
    float4 r;
    r.x = s.x * (1.f / 49.f) + p0.x;
    r.y = s.y * (1.f / 49.f) + p0.y;
    r.z = s.z * (1.f / 49.f) + p0.z;
    r.w = s.w * (1.f / 49.f) + p0.w;
    *(float4*)(Qm + (size_t)p * CDIM + c) = r;
}

// ---------------------------------------------------------------------------
// POSS[p][h][t] = Qm[p][h-slice] . Kbuf[PIX+t][h-slice]   (pos scores, all patches)
__global__ __launch_bounds__(256) void poss_k(const float* __restrict__ Kbuf,
                                              const float* __restrict__ Qm,
                                              float* __restrict__ POSS) {
    __shared__ float qsl[4 * HD];
    int pb = blockIdx.x * 4, h = blockIdx.y, tid = threadIdx.x;
    qsl[tid] = Qm[(size_t)(pb + (tid >> 6)) * CDIM + h * HD + (tid & 63)];
    __syncthreads();
    if (tid < 200) {
        int pp = tid / 50, t = tid % 50;
        const float* kp = Kbuf + (size_t)(PIX + t) * CDIM + h * HD;
        const float* q = &qsl[pp * HD];
        float dot = 0.f;
#pragma unroll
        for (int d = 0; d < HD; d += 4) {
            float4 kv = *(const float4*)&kp[d];
            dot += kv.x * q[d] + kv.y * q[d + 1] + kv.z * q[d + 2] + kv.w * q[d + 3];
        }
        POSS[(size_t)(pb + pp) * (NHEAD * NTOK) + h * NTOK + t] = dot;
    }
}

// ---------------------------------------------------------------------------
// TW[j][c] = (txt_j/||txt_j||) . out_w[:,c];  cconst[j] = (txt_j/||..||) . out_b
__global__ __launch_bounds__(256) void txtw_k(
    const float* __restrict__ txt, const float* __restrict__ out_w, const float* __restrict__ out_b,
    float* __restrict__ TW, float* __restrict__ cconst)
{
    __shared__ float ts[OUTD];
    __shared__ float red[256], redb[256];
    int j = blockIdx.x, cb = blockIdx.y, tid = threadIdx.x;

    float n2 = 0.f, db = 0.f;
    for (int o = tid; o < OUTD; o += 256) {
        float tv = txt[(size_t)j * OUTD + o];
        ts[o] = tv;
        n2 += tv * tv;
        db += tv * out_b[o];
    }
    red[tid] = n2; redb[tid] = db;
    __syncthreads();
    for (int s = 128; s > 0; s >>= 1) {
        if (tid < s) { red[tid] += red[tid + s]; redb[tid] += redb[tid + s]; }
        __syncthreads();
    }
    float inv = 1.f / sqrtf(red[0]);

    int c = cb * 256 + tid;
    float acc = 0.f;
    for (int o = 0; o < OUTD; ++o)
        acc += ts[o] * out_w[(size_t)o * CDIM + c];
    TW[(size_t)j * CDIM + c] = acc * inv;
    if (cb == 0 && tid == 0) cconst[j] = redb[0] * inv;
}

// ---------------------------------------------------------------------------
// TV[col][h*NTXT+j] = sum_d TW[j][h*64+d] * V[col][h*64+d]
__global__ __launch_bounds__(256) void tv_k(
    const float* __restrict__ TW, const float* __restrict__ Vbuf, float* __restrict__ TV)
{
    __shared__ float TWs[NTXT * HD];
    __shared__ float Vs[8 * HD];
    int cg = blockIdx.x, h = blockIdx.y, tid = threadIdx.x;
    int c0 = cg * 8;

    for (int idx = tid; idx < NTXT * HD; idx += 256) {
        int j = idx / HD, d = idx % HD;
        TWs[idx] = TW[(size_t)j * CDIM + h * HD + d];
    }
    for (int idx = tid; idx < 8 * HD; idx += 256) {
        int c = idx / HD, d = idx % HD;
        int col = c0 + c;
        Vs[idx] = (col < NKV) ? Vbuf[(size_t)col * CDIM + h * HD + d] : 0.f;
    }
    __syncthreads();

    for (int o = tid; o < 8 * NTXT; o += 256) {
        int c = o / NTXT, j = o % NTXT;
        int col = c0 + c;
        if (col >= NKV) continue;
        float acc = 0.f;
#pragma unroll
        for (int d = 0; d < HD; d += 4) {
            float4 tw = *(const float4*)&TWs[j * HD + d];
            float4 vv = *(const float4*)&Vs[c * HD + d];
            acc += tw.x * vv.x + tw.y * vv.y + tw.z * vv.z + tw.w * vv.w;
        }
        TV[(size_t)col * HJ + h * NTXT + j] = acc;
    }
}

// ---------------------------------------------------------------------------
// Fused per-(patch, 8-head-slice) scores + softmax + folded pooling, v3.
__global__ __launch_bounds__(384) void attn_fused_k(
    const float* __restrict__ Kbuf, const float* __restrict__ Qm,
    const float* __restrict__ TV, const float* __restrict__ POSS,
    float* __restrict__ pooledHJ)
{
    __shared__ float qs[8 * HD];       // q slice for 8 heads
    __shared__ float scf[8][NTOK];     // feature scores -> probs after softmax
    __shared__ float scp[8][NTOK];     // pos scores (from POSS)
    __shared__ int win[49];

    int flat = blockIdx.x;
    int s = (flat & 7) >> 1;
    int p = (flat >> 3) * 2 + (flat & 1);
    int h0 = s * 8;
    int pi = p / WO, pj = p % WO;
    int tid = threadIdx.x;

    if (tid < 128)
        *(float4*)&qs[tid * 4] = *(const float4*)(Qm + (size_t)p * CDIM + h0 * HD + tid * 4);
    if (tid < 49)
        win[tid] = (pi + tid / 7) * WF + (pj + tid % 7);
    for (int u = tid; u < 8 * NTOK; u += 384)
        scp[u / NTOK][u % NTOK] = POSS[(size_t)p * (NHEAD * NTOK) + h0 * NTOK + u];
    __syncthreads();

    // 392 feature dots (h, t=tt+1, row=win[tt]); 24 groups x 17 iters, stride-24.
    int grp = tid >> 4, gl = tid & 15;
    for (int i = 0; i < 17; ++i) {
        int pair = i * 24 + grp;
        if (pair < 392) {
            int h = pair / 49, tt = pair % 49;
            float4 kv = *(const float4*)(Kbuf + (size_t)win[tt] * CDIM + (h0 + h) * HD + gl * 4);
            float4 qv = *(const float4*)&qs[h * HD + gl * 4];
            float d = kv.x * qv.x + kv.y * qv.y + kv.z * qv.z + kv.w * qv.w;
            d += __shfl_xor(d, 1);
            d += __shfl_xor(d, 2);
            d += __shfl_xor(d, 4);
            d += __shfl_xor(d, 8);
            if (gl == 0) scf[h][tt + 1] = d;
        }
    }
    __syncthreads();

    // parallel softmax: group grp<8 = head, lanes cover tokens {gl, gl+16, gl+32, gl+48}
    if (tid < 128) {
        int h = grp;
        float sloc = 0.f;
#pragma unroll
        for (int i = 0; i < 4; ++i) {
            int t = gl + 16 * i;
            if (t >= 1 && t < NTOK) sloc += scf[h][t];
        }
        sloc += __shfl_xor(sloc, 1); sloc += __shfl_xor(sloc, 2);
        sloc += __shfl_xor(sloc, 4); sloc += __shfl_xor(sloc, 8);
        float s0 = sloc * (1.f / 49.f);

        float sc[4];
        float mloc = -1e30f;
#pragma unroll
        for (int i = 0; i < 4; ++i) {
            int t = gl + 16 * i;
            if (t < NTOK) {
                float base = (t == 0) ? s0 : scf[h][t];
                sc[i] = (base + scp[h][t]) * 0.125f;
                mloc = fmaxf(mloc, sc[i]);
            }
        }
        mloc = fmaxf(mloc, __shfl_xor(mloc, 1)); mloc = fmaxf(mloc, __shfl_xor(mloc, 2));
        mloc = fmaxf(mloc, __shfl_xor(mloc, 4)); mloc = fmaxf(mloc, __shfl_xor(mloc, 8));

        float ev[4];
        float eloc = 0.f;
#pragma unroll
        for (int i = 0; i < 4; ++i) {
            int t = gl + 16 * i;
            if (t < NTOK) { ev[i] = expf(sc[i] - mloc); eloc += ev[i]; }
        }
        eloc += __shfl_xor(eloc, 1); eloc += __shfl_xor(eloc, 2);
        eloc += __shfl_xor(eloc, 4); eloc += __shfl_xor(eloc, 8);
        float inv = 1.f / eloc;
#pragma unroll
        for (int i = 0; i < 4; ++i) {
            int t = gl + 16 * i;
            if (t < NTOK) scf[h][t] = ev[i] * inv;
        }
    }
    __syncthreads();

    // folded pooling for this slice's o-window (contiguous, coalesced)
    if (tid < 360) {
        int o = s * 360 + tid;
        int hloc = tid / 45;
        const float* apr = &scf[hloc][0];
        float lacc = 0.f, macc = 0.f;
#pragma unroll 7
        for (int t = 1; t < NTOK; ++t) {
            float a = apr[t];
            float v1 = TV[(size_t)win[t - 1] * HJ + o];
            float v2 = TV[(size_t)(PIX + t) * HJ + o];
            lacc += a * (v1 + v2);
            macc += v1;
        }
        float a0 = apr[0];
        lacc += a0 * (macc * (1.f / 49.f) + TV[(size_t)PIX * HJ + o]);
        pooledHJ[(size_t)p * HJ + o] = lacc;
    }
}

// ---------------------------------------------------------------------------
// finish: reduce pooledHJ over heads, add cconst, argmax -> bucket
__global__ __launch_bounds__(64) void finish_k(const float* __restrict__ pooledHJ,
                                               const float* __restrict__ cconst,
                                               int* __restrict__ bucket) {
    __shared__ float lg[NTXT];
    int p = blockIdx.x, lane = threadIdx.x;
    if (lane < NTXT) {
        float s = cconst[lane];
        const float* row = pooledHJ + (size_t)p * HJ;
#pragma unroll 8
        for (int h = 0; h < NHEAD; ++h) s += row[h * NTXT + lane];
        lg[lane] = s;
    }
    __syncthreads();
    if (lane == 0) {
        float best = lg[0]; int bi = 0;
        for (int j2 = 1; j2 < NTXT; ++j2)
            if (lg[j2] > best) { best = lg[j2]; bi = j2; }
        int bk = 0;
        const int bounds[5] = {8, 15, 22, 29, 36};
#pragma unroll
        for (int u = 0; u < 5; ++u) bk += (bi >= bounds[u]) ? 1 : 0;
        bucket[p] = bk;
    }
}

// ---------------------------------------------------------------------------
__global__ void votes_k(const int* __restrict__ bucket, float* __restrict__ maxval) {
    __shared__ int bk[NP];
    int tid = threadIdx.x;
    if (tid < NP) bk[tid] = bucket[tid];
    __syncthreads();
    if (tid < PIX) {
        int y = tid / WF, x = tid % WF;
        int cnt[6] = {0, 0, 0, 0, 0, 0};
        int i0 = (y - 6 < 0) ? 0 : y - 6;
        int i1 = (y > HO - 1) ? HO - 1 : y;
        int j0 = (x - 6 < 0) ? 0 : x - 6;
        int j1 = (x > WO - 1) ? WO - 1 : x;
        for (int i = i0; i <= i1; ++i)
            for (int j = j0; j <= j1; ++j)
                cnt[bk[i * WO + j]]++;
        int best = cnt[0], bi = 0;
#pragma unroll
        for (int ch = 1; ch < 6; ++ch)
            if (cnt[ch] > best) { best = cnt[ch]; bi = ch; }
        maxval[tid] = (bi > 0) ? 0.044194173824159216f : 0.f;
    }
}

__global__ void fill_k(const float* __restrict__ maxval, float* __restrict__ out) {
    int idx = blockIdx.x * 256 + threadIdx.x;
    const int HALF = OUTD * PIX;
    if (idx >= 2 * HALF) return;
    out[idx] = (idx < HALF) ? 0.f : maxval[idx % PIX];
}

// ---------------------------------------------------------------------------
extern "C" void kernel_launch(void* const* d_in, const int* in_sizes, int n_in,
                              void* d_out, int out_size, void* d_ws, size_t ws_size,
                              hipStream_t stream) {
    const float* imgf = (const float*)d_in[0];
    const float* txt  = (const float*)d_in[1];
    const float* pos  = (const float*)d_in[2];
    const float* q_w  = (const float*)d_in[3];
    const float* q_b  = (const float*)d_in[4];
    const float* k_w  = (const float*)d_in[5];
    const float* k_b  = (const float*)d_in[6];
    const float* v_w  = (const float*)d_in[7];
    const float* v_b  = (const float*)d_in[8];
    const float* o_w  = (const float*)d_in[9];
    const float* o_b  = (const float*)d_in[10];

    const float* feat1 = imgf + (size_t)1 * CDIM * PIX;   // only batch B-1=1 matters

    float* ws = (float*)d_ws;
    float* Kbuf  = ws;                                   // 640*2048
    float* Vbuf  = Kbuf + (size_t)NROWS * CDIM;
    float* Qfull = Vbuf + (size_t)NROWS * CDIM;
    float* Qm    = Qfull + (size_t)NROWS * CDIM;         // 324*2048
    float* TW    = Qm + (size_t)NP * CDIM;               // 45*2048
    float* cconst = TW + (size_t)NTXT * CDIM;            // 64
    float* TV    = cconst + 64;                          // 626*1440
    float* pooledHJ = TV + (size_t)NKV * HJ;             // 324*1440
    float* POSS  = pooledHJ + (size_t)NP * HJ;           // 324*1600
    int*   bucket = (int*)(POSS + (size_t)NP * NHEAD * NTOK);  // 324
    float* maxval = (float*)(bucket + NP);               // 576
    size_t foff = (size_t)(maxval + 576 - ws);
    foff = (foff + 3) & ~(size_t)3;                      // 16B align
    ushort* WhK = (ushort*)(ws + foff);                  // each 2048*2048
    ushort* WlK = WhK + (size_t)CDIM * CDIM;
    ushort* WhV = WlK + (size_t)CDIM * CDIM;
    ushort* WlV = WhV + (size_t)CDIM * CDIM;
    ushort* WhQ = WlV + (size_t)CDIM * CDIM;
    ushort* WlQ = WhQ + (size_t)CDIM * CDIM;
    ushort* Xh  = WlQ + (size_t)CDIM * CDIM;             // 640*2048
    ushort* Xl  = Xh + (size_t)NROWS * CDIM;

    split_w_k<<<dim3(6144), dim3(256), 0, stream>>>(k_w, v_w, q_w, WhK, WlK, WhV, WlV, WhQ, WlQ);
    split_xt_k<<<dim3(9, 32), dim3(256), 0, stream>>>(feat1, Xh, Xl);
    split_pos_k<<<dim3(128), dim3(256), 0, stream>>>(pos, Xh, Xl);
    gemm_bf16_k<<<dim3(16, 10, 3), dim3(256), 0, stream>>>(WhK, WlK, WhV, WlV, WhQ, WlQ,
                                                           Xh, Xl, k_b, v_b, q_b, Kbuf, Vbuf, Qfull);
    qmean_k<<<dim3(NP, 2), dim3(256), 0, stream>>>(Qfull, Qm);
    poss_k<<<dim3(81, 32), dim3(256), 0, stream>>>(Kbuf, Qm, POSS);
    txtw_k<<<dim3(NTXT, 8), dim3(256), 0, stream>>>(txt, o_w, o_b, TW, cconst);
    tv_k<<<dim3(79, 32), dim3(256), 0, stream>>>(TW, Vbuf, TV);
    attn_fused_k<<<dim3(NP * 4), dim3(384), 0, stream>>>(Kbuf, Qm, TV, POSS, pooledHJ);
    finish_k<<<dim3(NP), dim3(64), 0, stream>>>(pooledHJ, cconst, bucket);
    votes_k<<<dim3(1), dim3(576), 0, stream>>>(bucket, maxval);
    fill_k<<<dim3(2304), dim3(256), 0, stream>>>(maxval, (float*)d_out);
}